// Round 3
// baseline (325.713 us; speedup 1.0000x reference)
//
#include <hip/hip_runtime.h>
#include <cstdint>
#include <cstddef>

typedef unsigned short ushort_t;
typedef __attribute__((ext_vector_type(8))) short short8;
typedef __attribute__((ext_vector_type(4))) float f32x4;
typedef __attribute__((ext_vector_type(4))) _Float16 half4;
typedef __attribute__((ext_vector_type(2))) _Float16 half2;
typedef __attribute__((ext_vector_type(2))) __fp16 fp16v2;
struct half4x2 { half4 lo, hi; };
struct half2x2 { half2 lo, hi; };

__device__ __forceinline__ unsigned short f2bf(float f) {
    unsigned u = __float_as_uint(f);
    u += 0x7fffu + ((u >> 16) & 1u);
    return (unsigned short)(u >> 16);
}
__device__ __forceinline__ float bf2f(unsigned short h) {
    return __uint_as_float((unsigned)h << 16);
}
__device__ __forceinline__ ushort_t f2h(float f) {
    _Float16 h = (_Float16)f;
    return __builtin_bit_cast(unsigned short, h);
}
__device__ __forceinline__ f32x4 zero4() {
    f32x4 z; z[0]=0.f; z[1]=0.f; z[2]=0.f; z[3]=0.f; return z;
}
__device__ __forceinline__ half4 pk4(float a, float b, float cc, float d) {
    half2x2 t;
    t.lo = __builtin_bit_cast(half2, (fp16v2)__builtin_amdgcn_cvt_pkrtz(a, b));
    t.hi = __builtin_bit_cast(half2, (fp16v2)__builtin_amdgcn_cvt_pkrtz(cc, d));
    return __builtin_bit_cast(half4, t);
}
__device__ __forceinline__ void gld_lds16(const ushort_t* g, ushort_t* l) {
    __builtin_amdgcn_global_load_lds(
        (const __attribute__((address_space(1))) void*)g,
        (__attribute__((address_space(3))) void*)l, 16, 0, 0);
}

// ---------------- fused fp32->bf16 convert (x + 4 weights) + rope table, one launch ----------------
__global__ void cvt_all(const float* __restrict__ x,
                        const float* __restrict__ wq, const float* __restrict__ wk,
                        const float* __restrict__ wv, const float* __restrict__ wo,
                        ushort_t* __restrict__ xb,
                        ushort_t* __restrict__ wqb, ushort_t* __restrict__ wkb,
                        ushort_t* __restrict__ wvb, ushort_t* __restrict__ wob,
                        float2* __restrict__ tab) {
    int idx = blockIdx.x * 256 + threadIdx.x;   // grid 12544 blocks exactly
    if (idx >= 3145728) {                        // rope table: 65536 entries
        int i = idx - 3145728;
        int t = i >> 5, p = i & 31;
        float freq = __expf((float)p * -0.2878231366242557f);  // 10000^(-p/32)
        float sn, cs;
        sincosf((float)t * freq, &sn, &cs);
        tab[i] = make_float2(cs, sn);
        return;
    }
    const float* src; ushort_t* dst; int off;
    if (idx < 2097152) { src = x; dst = xb; off = idx; }
    else {
        int r = idx - 2097152;
        int w = r >> 18;
        off = r & 262143;
        src = (w == 0) ? wq : (w == 1) ? wk : (w == 2) ? wv : wo;
        dst = (w == 0) ? wqb : (w == 1) ? wkb : (w == 2) ? wvb : wob;
    }
    float4 v = ((const float4*)src)[off];
    ushort_t o[4];
    o[0] = f2bf(v.x); o[1] = f2bf(v.y); o[2] = f2bf(v.z); o[3] = f2bf(v.w);
    *(ushort4*)(dst + 4*(size_t)off) = *(const ushort4*)o;
}

// ---------------- GEMM core B (pipelined): BM=256 BN=128 BK=64, 8 waves,
// 3-deep LDS ring, counted vmcnt(6), setprio, XOR-swizzled LDS.
__device__ __forceinline__ void gemm_pipe256(const ushort_t* __restrict__ A,
                                             const ushort_t* __restrict__ W,
                                             ushort_t* __restrict__ As,   // 3*16384
                                             ushort_t* __restrict__ Bs,   // 3*8192
                                             int m0, int n0, f32x4 (&acc)[4][4]) {
    const int tid  = threadIdx.x;
    const int wave = tid >> 6, lane = tid & 63;
    const int wm = (wave >> 1) * 64, wn = (wave & 1) * 64;
    const int q = lane >> 4, c = lane & 15;
    const int srow = lane >> 3;            // 0..7
    const int gch  = (lane & 7) ^ srow;    // swizzled source chunk

    const ushort_t* ag = A + (size_t)(m0 + wave * 8 + srow) * 1024 + gch * 8;
    const ushort_t* bg = W + (size_t)(n0 + wave * 8 + srow) * 1024 + gch * 8;
    ushort_t* adst = As + wave * 512;
    ushort_t* bdst = Bs + wave * 512;

    // prologue: stage tile0 -> buf0, tile1 -> buf1 (6 loads each, per thread)
#pragma unroll
    for (int n = 0; n < 4; ++n) gld_lds16(ag + (size_t)n * 65536,      adst + n * 4096);
#pragma unroll
    for (int n = 0; n < 2; ++n) gld_lds16(bg + (size_t)n * 65536,      bdst + n * 4096);
#pragma unroll
    for (int n = 0; n < 4; ++n) gld_lds16(ag + (size_t)n * 65536 + 64, adst + 16384 + n * 4096);
#pragma unroll
    for (int n = 0; n < 2; ++n) gld_lds16(bg + (size_t)n * 65536 + 64, bdst + 8192 + n * 4096);
    asm volatile("s_waitcnt vmcnt(6)" ::: "memory");   // tile0 landed; tile1 in flight
    __builtin_amdgcn_s_barrier();

    const int ch0 = (q ^ (c & 7)) * 8;
    const int ch1 = ((4 + q) ^ (c & 7)) * 8;
    int cur = 0;
    for (int t = 0; t < 16; ++t) {
        const int nx2 = (cur >= 1) ? cur - 1 : 2;          // (t+2)%3
        const ushort_t* ab = As + cur * 16384 + (wm + c) * 64;
        const ushort_t* bb = Bs + cur * 8192  + (wn + c) * 64;
        const int kc = (t + 2) * 64;
        const bool pf = (t < 14);
        short8 af[4], bf[4];

        // ---- phase 0: sk=0 frags, stage A0,A1,B0 of tile t+2
#pragma unroll
        for (int i = 0; i < 4; ++i) af[i] = *(const short8*)(ab + i * 1024 + ch0);
#pragma unroll
        for (int j = 0; j < 4; ++j) bf[j] = *(const short8*)(bb + j * 1024 + ch0);
        if (pf) {
            gld_lds16(ag + kc,           adst + nx2 * 16384);
            gld_lds16(ag + 65536 + kc,   adst + nx2 * 16384 + 4096);
            gld_lds16(bg + kc,           bdst + nx2 * 8192);
        }
        __builtin_amdgcn_s_barrier();
        asm volatile("s_waitcnt lgkmcnt(0)" ::: "memory");
        __builtin_amdgcn_s_setprio(1);
#pragma unroll
        for (int i = 0; i < 4; ++i)
#pragma unroll
            for (int j = 0; j < 4; ++j)
                acc[i][j] = __builtin_amdgcn_mfma_f32_16x16x32_bf16(af[i], bf[j], acc[i][j], 0, 0, 0);
        __builtin_amdgcn_s_setprio(0);
        __builtin_amdgcn_s_barrier();

        // ---- phase 1: sk=1 frags, stage A2,A3,B1 of tile t+2
#pragma unroll
        for (int i = 0; i < 4; ++i) af[i] = *(const short8*)(ab + i * 1024 + ch1);
#pragma unroll
        for (int j = 0; j < 4; ++j) bf[j] = *(const short8*)(bb + j * 1024 + ch1);
        if (pf) {
            gld_lds16(ag + 131072 + kc,  adst + nx2 * 16384 + 8192);
            gld_lds16(ag + 196608 + kc,  adst + nx2 * 16384 + 12288);
            gld_lds16(bg + 65536 + kc,   bdst + nx2 * 8192 + 4096);
        }
        __builtin_amdgcn_s_barrier();
        asm volatile("s_waitcnt lgkmcnt(0)" ::: "memory");
        __builtin_amdgcn_s_setprio(1);
#pragma unroll
        for (int i = 0; i < 4; ++i)
#pragma unroll
            for (int j = 0; j < 4; ++j)
                acc[i][j] = __builtin_amdgcn_mfma_f32_16x16x32_bf16(af[i], bf[j], acc[i][j], 0, 0, 0);
        __builtin_amdgcn_s_setprio(0);
        // counted wait: retire tile t+1's 6 loads, leave tile t+2's 6 in flight
        if (pf) { asm volatile("s_waitcnt vmcnt(6)" ::: "memory"); }
        else    { asm volatile("s_waitcnt vmcnt(0)" ::: "memory"); }
        __builtin_amdgcn_s_barrier();
        cur = (cur == 2) ? 0 : cur + 1;
    }
}

// Persistent fused QKV: 256 blocks (1/CU exactly), each owns 3 tiles sharing
// one 256-row A-panel (A fetched once, L2-hot for tiles 2,3). One flat 48-step
// pipe256 pipeline (pointers switch tile every 16 steps): single cold prologue,
// ring/vmcnt(6) ledger uninterrupted; per-tile RoPE/scatter epilogue runs at
// the start of the next step so its stores retire under subsequent compute.
// XCD mapping: the 8 blocks of one m-panel share one XCD (b&7 = XCD).
__global__ __launch_bounds__(512) void gemm_qkv_kernel(
    const ushort_t* __restrict__ X, const ushort_t* __restrict__ Wq,
    const ushort_t* __restrict__ Wk, const ushort_t* __restrict__ Wv,
    const float2* __restrict__ tab,
    ushort_t* __restrict__ Q, ushort_t* __restrict__ Kt, ushort_t* __restrict__ Vt) {
    __shared__ ushort_t As[3 * 16384];
    __shared__ ushort_t Bs[3 * 8192];
    const int bid = blockIdx.x;                 // 0..255
    const int x8  = bid & 7;                    // XCD (round-robin heuristic)
    const int jj  = bid >> 3;                   // 0..31
    const int my  = x8 * 4 + (jj & 3);          // 0..31: panel; 8 panel-mates share XCD
    const int m0  = my * 256;
    const int nbase = (jj >> 2) * 3;            // first of this block's 3 n24 slices

    const int tid  = threadIdx.x;
    const int wave = tid >> 6, lane = tid & 63;
    const int wm = (wave >> 1) * 64, wn = (wave & 1) * 64;
    const int q = lane >> 4, c = lane & 15;
    const int srow = lane >> 3;
    const int gch  = (lane & 7) ^ srow;

    const ushort_t* ag = X + (size_t)(m0 + wave * 8 + srow) * 1024 + gch * 8;
    // per-tile B pointers (uniform ternary select later; no indexed array)
    const int n24_0 = nbase, n24_1 = nbase + 1, n24_2 = nbase + 2;
    const ushort_t* wsel0 = (n24_0 >> 3) == 0 ? Wq : (n24_0 >> 3) == 1 ? Wk : Wv;
    const ushort_t* wsel1 = (n24_1 >> 3) == 0 ? Wq : (n24_1 >> 3) == 1 ? Wk : Wv;
    const ushort_t* wsel2 = (n24_2 >> 3) == 0 ? Wq : (n24_2 >> 3) == 1 ? Wk : Wv;
    const ushort_t* bg0 = wsel0 + (size_t)(((n24_0 & 7) * 128) + wave * 8 + srow) * 1024 + gch * 8;
    const ushort_t* bg1 = wsel1 + (size_t)(((n24_1 & 7) * 128) + wave * 8 + srow) * 1024 + gch * 8;
    const ushort_t* bg2 = wsel2 + (size_t)(((n24_2 & 7) * 128) + wave * 8 + srow) * 1024 + gch * 8;
    ushort_t* adst = As + wave * 512;
    ushort_t* bdst = Bs + wave * 512;

    f32x4 acc[4][4];
#pragma unroll
    for (int i = 0; i < 4; ++i)
#pragma unroll
        for (int j = 0; j < 4; ++j) acc[i][j] = zero4();

    auto bgof = [&](int s) -> const ushort_t* {
        const int tl = s >> 4;
        return (tl == 0) ? bg0 : (tl == 1) ? bg1 : bg2;
    };
    auto stage_p0 = [&](int s, int buf) {       // A chunks 0,1 + B chunk 0
        const int kc = (s & 15) * 64;
        const ushort_t* bg = bgof(s);
        gld_lds16(ag + kc,           adst + buf * 16384);
        gld_lds16(ag + 65536 + kc,   adst + buf * 16384 + 4096);
        gld_lds16(bg + kc,           bdst + buf * 8192);
    };
    auto stage_p1 = [&](int s, int buf) {       // A chunks 2,3 + B chunk 1
        const int kc = (s & 15) * 64;
        const ushort_t* bg = bgof(s);
        gld_lds16(ag + 131072 + kc,  adst + buf * 16384 + 8192);
        gld_lds16(ag + 196608 + kc,  adst + buf * 16384 + 12288);
        gld_lds16(bg + 65536 + kc,   bdst + buf * 8192 + 4096);
    };
    auto epi = [&](int tile) {                  // RoPE + layout-scatter for one tile
        const int n24 = nbase + tile;
        const int which = n24 >> 3;
        const int nloc0 = (n24 & 7) * 128;
        const float scale = (which == 0) ? 0.18033688011112042f : 1.0f;  // 0.125*log2(e)
#pragma unroll
        for (int i = 0; i < 4; ++i)
#pragma unroll
            for (int j = 0; j < 4; ++j) {
                int nn = nloc0 + wn + j * 16 + c;    // col within matrix: h*64+d
                int d = nn & 63, h = nn >> 6;
                int pidx = d >> 1;
                float sgn = (d & 1) ? 1.f : -1.f;
#pragma unroll
                for (int r = 0; r < 4; ++r) {
                    int mm = m0 + wm + i * 16 + q * 4 + r;   // row: b*2048+t
                    int b = mm >> 11, t = mm & 2047;
                    float val = acc[i][j][r];
                    if (which == 0) {      // Q: rope + (B,H,T,64) bf16 row-major
                        float partner = __shfl_xor(val, 1);
                        float2 cs = tab[t * 32 + pidx];
                        val = (val * cs.x + sgn * partner * cs.y) * scale;
                        Q[((size_t)((b << 4) + h) * 2048 + t) * 64 + d] = f2bf(val);
                    } else if (which == 1) {  // K: rope + scatter into tiled bf16 layout
                        float partner = __shfl_xor(val, 1);
                        float2 cs = tab[t * 32 + pidx];
                        val = val * cs.x + sgn * partner * cs.y;
                        int kb = t >> 6, jn = (t >> 4) & 3, cc2 = t & 15;
                        int ks2 = d >> 5, qq2 = (d >> 3) & 3, e = d & 7;
                        int lane2 = qq2 * 16 + cc2;
                        Kt[((((size_t)((b << 4) + h) * 32 + kb) * 8 + jn * 2 + ks2) << 9) + lane2 * 8 + e] = f2bf(val);
                    } else {               // V: scatter into tiled f16 layout
                        int kb = t >> 6, kl = t & 63;
                        int jn = kl >> 4, qq2 = (kl >> 2) & 3;
                        int e = ((jn & 1) << 2) | (kl & 3);
                        int p = ((d >> 4) << 1) | (jn >> 1);
                        int lane2 = qq2 * 16 + (d & 15);
                        Vt[((((size_t)((b << 4) + h) * 32 + kb) * 8 + p) << 9) + lane2 * 8 + e] = f2h(val);
                    }
                }
            }
#pragma unroll
        for (int i = 0; i < 4; ++i)
#pragma unroll
            for (int j = 0; j < 4; ++j) acc[i][j] = zero4();
    };

    // prologue: stage step0 -> buf0, step1 -> buf1
    stage_p0(0, 0); stage_p1(0, 0);
    stage_p0(1, 1); stage_p1(1, 1);
    asm volatile("s_waitcnt vmcnt(6)" ::: "memory");   // step0 landed; step1 in flight
    __builtin_amdgcn_s_barrier();

    const int ch0 = (q ^ (c & 15 & 7)) * 8;   // == (q ^ (c & 7)) * 8
    const int ch1 = ((4 + q) ^ (c & 7)) * 8;
    int cur = 0;
    for (int s = 0; s < 48; ++s) {
        if (s && (s & 15) == 0) epi((s >> 4) - 1);      // prev tile's epilogue; stores
                                                        // retire under next 16 steps
        const int nx2 = (cur >= 1) ? cur - 1 : 2;       // (s+2)%3
        const ushort_t* ab = As + cur * 16384 + (wm + c) * 64;
        const ushort_t* bb = Bs + cur * 8192  + (wn + c) * 64;
        const bool pf = (s < 46);
        short8 af[4], bf[4];

        // ---- phase 0
#pragma unroll
        for (int i = 0; i < 4; ++i) af[i] = *(const short8*)(ab + i * 1024 + ch0);
#pragma unroll
        for (int j = 0; j < 4; ++j) bf[j] = *(const short8*)(bb + j * 1024 + ch0);
        if (pf) stage_p0(s + 2, nx2);
        __builtin_amdgcn_s_barrier();
        asm volatile("s_waitcnt lgkmcnt(0)" ::: "memory");
        __builtin_amdgcn_s_setprio(1);
#pragma unroll
        for (int i = 0; i < 4; ++i)
#pragma unroll
            for (int j = 0; j < 4; ++j)
                acc[i][j] = __builtin_amdgcn_mfma_f32_16x16x32_bf16(af[i], bf[j], acc[i][j], 0, 0, 0);
        __builtin_amdgcn_s_setprio(0);
        __builtin_amdgcn_s_barrier();

        // ---- phase 1
#pragma unroll
        for (int i = 0; i < 4; ++i) af[i] = *(const short8*)(ab + i * 1024 + ch1);
#pragma unroll
        for (int j = 0; j < 4; ++j) bf[j] = *(const short8*)(bb + j * 1024 + ch1);
        if (pf) stage_p1(s + 2, nx2);
        __builtin_amdgcn_s_barrier();
        asm volatile("s_waitcnt lgkmcnt(0)" ::: "memory");
        __builtin_amdgcn_s_setprio(1);
#pragma unroll
        for (int i = 0; i < 4; ++i)
#pragma unroll
            for (int j = 0; j < 4; ++j)
                acc[i][j] = __builtin_amdgcn_mfma_f32_16x16x32_bf16(af[i], bf[j], acc[i][j], 0, 0, 0);
        __builtin_amdgcn_s_setprio(0);
        // counted wait: retire step s+1's 6 loads, leave s+2's in flight.
        // (On epilogue steps the younger stores inflate the count; in-order
        //  retirement still guarantees s+1's loads are done at <=6.)
        if (pf) { asm volatile("s_waitcnt vmcnt(6)" ::: "memory"); }
        else    { asm volatile("s_waitcnt vmcnt(0)" ::: "memory"); }
        __builtin_amdgcn_s_barrier();
        cur = (cur == 2) ? 0 : cur + 1;
    }
    epi(2);
}

__global__ __launch_bounds__(512) void gemm_out_kernel(
    const ushort_t* __restrict__ A, const ushort_t* __restrict__ Wo,
    float* __restrict__ OUT) {
    __shared__ ushort_t As[3 * 16384];
    __shared__ ushort_t Bs[3 * 8192];
    // 256 blocks (32 m-tiles x 8 n-tiles) = exactly 1/CU, XCD-swizzled
    const int orig = blockIdx.x;
    const int wg = (orig & 7) * 32 + (orig >> 3);
    const int m0 = (wg >> 3) * 256, n0 = (wg & 7) * 128;

    f32x4 acc[4][4];
#pragma unroll
    for (int i = 0; i < 4; ++i)
#pragma unroll
        for (int j = 0; j < 4; ++j) acc[i][j] = zero4();

    gemm_pipe256(A, Wo, As, Bs, m0, n0, acc);

    const int lane = threadIdx.x & 63, wave = threadIdx.x >> 6;
    const int q = lane >> 4, c = lane & 15;
    const int wm = (wave >> 1) * 64, wn = (wave & 1) * 64;
#pragma unroll
    for (int i = 0; i < 4; ++i)
#pragma unroll
        for (int j = 0; j < 4; ++j)
#pragma unroll
            for (int r = 0; r < 4; ++r) {
                int mm = m0 + wm + i*16 + q*4 + r;
                int nn = n0 + wn + j*16 + c;
                OUT[(size_t)mm * 1024 + nn] = acc[i][j][r];
            }
}

// ---------------- Flash attention v6: LDS-staged K/V, 4 waves x 32 queries ----------------
__global__ __launch_bounds__(256, 3) void flash_kernel(
    const ushort_t* __restrict__ Q, const ushort_t* __restrict__ Kt,
    const ushort_t* __restrict__ Vt, ushort_t* __restrict__ AO) {
    __shared__ ushort_t Ks[4096];   // 64x64 bf16 K tile, fragment-tiled
    __shared__ ushort_t Vs[4096];   // 64x64 f16 V tile, fragment-tiled
    const int bh = blockIdx.x;
    const int c0 = 15 - blockIdx.y;             // LPT: big chunks first
    const int w  = threadIdx.x >> 6, lane = threadIdx.x & 63;
    const int q = lane >> 4, c = lane & 15;
    const int qlo = c0 * 128;
    const int nt  = 2 * c0 + 2;                 // 64-key tiles
    const int wq0 = qlo + w * 32;               // this wave's first query
    const int b = bh >> 4, hh = bh & 15;

    const ushort_t* Qp = Q + (size_t)bh * 131072;
    const size_t tb = (size_t)bh * 131072;

    short8 qf[2][2];
#pragma unroll
    for (int m = 0; m < 2; ++m)
#pragma unroll
        for (int ks = 0; ks < 2; ++ks)
            qf[m][ks] = *(const short8*)(Qp + (size_t)(wq0 + m*16 + c) * 64 + ks * 32 + q * 8);

    f32x4 ot[2][4];
#pragma unroll
    for (int m = 0; m < 2; ++m)
#pragma unroll
        for (int dj = 0; dj < 4; ++dj) ot[m][dj] = zero4();
    float lpart[2] = {0.f, 0.f};

    for (int kb = 0; kb < nt; ++kb) {
        __syncthreads();                        // prior tile's LDS reads done
        const ushort_t* kt = Kt + tb + (size_t)kb * 4096;
        const ushort_t* vt = Vt + tb + (size_t)kb * 4096;
#pragma unroll
        for (int s = 0; s < 2; ++s) {
            gld_lds16(kt + (s*4 + w)*512 + lane*8, Ks + (s*4 + w)*512);
            gld_lds16(vt + (s*4 + w)*512 + lane*8, Vs + (s*4 + w)*512);
        }
        asm volatile("s_waitcnt vmcnt(0)" ::: "memory");
        __syncthreads();

        if (kb * 64 > wq0 + 31) continue;       // fully-masked tile for this wave

        // ---- S^T = K Q^T : row=key(q*4+r), col=query(c)
        f32x4 st[2][4];
#pragma unroll
        for (int jn = 0; jn < 4; ++jn) {
            short8 kf0 = *(const short8*)(Ks + (jn*2+0)*512 + lane*8);
            short8 kf1 = *(const short8*)(Ks + (jn*2+1)*512 + lane*8);
#pragma unroll
            for (int m = 0; m < 2; ++m) {
                f32x4 t0 = __builtin_amdgcn_mfma_f32_16x16x32_bf16(kf0, qf[m][0], zero4(), 0, 0, 0);
                st[m][jn] = __builtin_amdgcn_mfma_f32_16x16x32_bf16(kf1, qf[m][1], t0, 0, 0, 0);
            }
        }
        if (kb * 64 + 63 > wq0) {               // partial (diagonal) tile: mask
#pragma unroll
            for (int m = 0; m < 2; ++m) {
                int query = wq0 + m * 16 + c;
#pragma unroll
                for (int jn = 0; jn < 4; ++jn)
#pragma unroll
                    for (int r = 0; r < 4; ++r)
                        if (kb * 64 + jn * 16 + q * 4 + r > query) st[m][jn][r] = -1e30f;
            }
        }
        // ---- p = exp2(s'); per-lane l partials; pack f16 B-frags
        half4 pa[2][4];
#pragma unroll
        for (int m = 0; m < 2; ++m)
#pragma unroll
            for (int jn = 0; jn < 4; ++jn) {
                float p0 = exp2f(st[m][jn][0]), p1 = exp2f(st[m][jn][1]);
                float p2 = exp2f(st[m][jn][2]), p3 = exp2f(st[m][jn][3]);
                lpart[m] += (p0 + p1) + (p2 + p3);
                pa[m][jn] = pk4(p0, p1, p2, p3);
            }
        // ---- O^T += V^T P^T
#pragma unroll
        for (int jnp = 0; jnp < 2; ++jnp)
#pragma unroll
            for (int dj = 0; dj < 4; ++dj) {
                half4x2 vv = __builtin_bit_cast(half4x2,
                    *(const short8*)(Vs + (dj*2 + jnp)*512 + lane*8));
#pragma unroll
                for (int m = 0; m < 2; ++m) {
                    ot[m][dj] = __builtin_amdgcn_mfma_f32_16x16x16f16(vv.lo, pa[m][2*jnp],   ot[m][dj], 0, 0, 0);
                    ot[m][dj] = __builtin_amdgcn_mfma_f32_16x16x16f16(vv.hi, pa[m][2*jnp+1], ot[m][dj], 0, 0, 0);
                }
            }
    }

    // ---- epilogue: quad-reduce l (keys on lanes c,c+16,c+32,c+48), normalize, store
#pragma unroll
    for (int m = 0; m < 2; ++m) {
        float l = lpart[m];
        l += __shfl_xor(l, 16);
        l += __shfl_xor(l, 32);
        float inv = 1.f / l;
        int t = wq0 + m * 16 + c;
        ushort_t* base = AO + ((size_t)b * 2048 + t) * 1024 + hh * 64;
#pragma unroll
        for (int dj = 0; dj < 4; ++dj) {
            ushort4 o;
            o.x = f2bf(ot[m][dj][0] * inv);
            o.y = f2bf(ot[m][dj][1] * inv);
            o.z = f2bf(ot[m][dj][2] * inv);
            o.w = f2bf(ot[m][dj][3] * inv);
            *(ushort4*)(base + dj * 16 + q * 4) = o;
        }
    }
}

extern "C" void kernel_launch(void* const* d_in, const int* in_sizes, int n_in,
                              void* d_out, int out_size, void* d_ws, size_t ws_size,
                              hipStream_t stream) {
    const float* x  = (const float*)d_in[0];
    const float* Wq = (const float*)d_in[2];
    const float* Wk = (const float*)d_in[3];
    const float* Wv = (const float*)d_in[4];
    const float* Wo = (const float*)d_in[5];
    float* out = (float*)d_out;

    ushort_t* ws  = (ushort_t*)d_ws;
    ushort_t* Xb  = ws;                 // 8192x1024 bf16; reused as AO after projections
    ushort_t* Qb  = ws + 8388608;
    ushort_t* Ktb = ws + 16777216;      // bf16, MFMA-fragment-tiled (bh,kb,p,lane,8)
    ushort_t* Vtb = ws + 25165824;      // f16,  MFMA-fragment-tiled (bh,kb,p,lane,8)
    ushort_t* Wqb = ws + 33554432;
    ushort_t* Wkb = Wqb + 1048576;
    ushort_t* Wvb = Wkb + 1048576;
    ushort_t* Wob = Wvb + 1048576;
    float2*   tab = (float2*)(ws + 37748736);   // 512 KB rope table

    cvt_all<<<12544, 256, 0, stream>>>(x, Wq, Wk, Wv, Wo, Xb, Wqb, Wkb, Wvb, Wob, tab);

    // persistent fused QKV: 256 blocks x 3 tiles, flat 48-step pipeline
    gemm_qkv_kernel<<<256, 512, 0, stream>>>(Xb, Wqb, Wkb, Wvb, tab, Qb, Ktb, Vtb);

    flash_kernel<<<dim3(64, 16), 256, 0, stream>>>(Qb, Ktb, Vtb, Xb);

    gemm_out_kernel<<<256, 512, 0, stream>>>(Xb, Wob, out);
}

// Round 4
// 289.039 us; speedup vs baseline: 1.1269x; 1.1269x over previous
//
#include <hip/hip_runtime.h>
#include <cstdint>
#include <cstddef>

typedef unsigned short ushort_t;
typedef __attribute__((ext_vector_type(8))) short short8;
typedef __attribute__((ext_vector_type(4))) float f32x4;
typedef __attribute__((ext_vector_type(4))) _Float16 half4;
typedef __attribute__((ext_vector_type(2))) _Float16 half2;
typedef __attribute__((ext_vector_type(2))) __fp16 fp16v2;
struct half4x2 { half4 lo, hi; };
struct half2x2 { half2 lo, hi; };

__device__ __forceinline__ unsigned short f2bf(float f) {
    unsigned u = __float_as_uint(f);
    u += 0x7fffu + ((u >> 16) & 1u);
    return (unsigned short)(u >> 16);
}
__device__ __forceinline__ float bf2f(unsigned short h) {
    return __uint_as_float((unsigned)h << 16);
}
__device__ __forceinline__ ushort_t f2h(float f) {
    _Float16 h = (_Float16)f;
    return __builtin_bit_cast(unsigned short, h);
}
__device__ __forceinline__ f32x4 zero4() {
    f32x4 z; z[0]=0.f; z[1]=0.f; z[2]=0.f; z[3]=0.f; return z;
}
__device__ __forceinline__ half4 pk4(float a, float b, float cc, float d) {
    half2x2 t;
    t.lo = __builtin_bit_cast(half2, (fp16v2)__builtin_amdgcn_cvt_pkrtz(a, b));
    t.hi = __builtin_bit_cast(half2, (fp16v2)__builtin_amdgcn_cvt_pkrtz(cc, d));
    return __builtin_bit_cast(half4, t);
}
__device__ __forceinline__ void gld_lds16(const ushort_t* g, ushort_t* l) {
    __builtin_amdgcn_global_load_lds(
        (const __attribute__((address_space(1))) void*)g,
        (__attribute__((address_space(3))) void*)l, 16, 0, 0);
}

// ---------------- fused fp32->bf16 convert (x + 4 weights) + rope table, one launch ----------------
__global__ void cvt_all(const float* __restrict__ x,
                        const float* __restrict__ wq, const float* __restrict__ wk,
                        const float* __restrict__ wv, const float* __restrict__ wo,
                        ushort_t* __restrict__ xb,
                        ushort_t* __restrict__ wqb, ushort_t* __restrict__ wkb,
                        ushort_t* __restrict__ wvb, ushort_t* __restrict__ wob,
                        float2* __restrict__ tab) {
    int idx = blockIdx.x * 256 + threadIdx.x;   // grid 12544 blocks exactly
    if (idx >= 3145728) {                        // rope table: 65536 entries
        int i = idx - 3145728;
        int t = i >> 5, p = i & 31;
        float freq = __expf((float)p * -0.2878231366242557f);  // 10000^(-p/32)
        float sn, cs;
        sincosf((float)t * freq, &sn, &cs);
        tab[i] = make_float2(cs, sn);
        return;
    }
    const float* src; ushort_t* dst; int off;
    if (idx < 2097152) { src = x; dst = xb; off = idx; }
    else {
        int r = idx - 2097152;
        int w = r >> 18;
        off = r & 262143;
        src = (w == 0) ? wq : (w == 1) ? wk : (w == 2) ? wv : wo;
        dst = (w == 0) ? wqb : (w == 1) ? wkb : (w == 2) ? wvb : wob;
    }
    float4 v = ((const float4*)src)[off];
    ushort_t o[4];
    o[0] = f2bf(v.x); o[1] = f2bf(v.y); o[2] = f2bf(v.z); o[3] = f2bf(v.w);
    *(ushort4*)(dst + 4*(size_t)off) = *(const ushort4*)o;
}

// ---------------- GEMM core A (proven 113 us on qkv): BM=BN=128, BK=64, 4 waves,
// 32 KiB LDS -> multi-block/CU co-residency hides the barrier drain (m114).
// XOR-swizzled LDS, C = A(Mx1024) W(Nx1024)^T.
__device__ __forceinline__ void gemm_core(const ushort_t* __restrict__ A,
                                          const ushort_t* __restrict__ W,
                                          ushort_t* As, ushort_t* Bs,
                                          int m0, int n0, f32x4 (&acc)[4][4]) {
    const int tid  = threadIdx.x;
    const int wave = tid >> 6, lane = tid & 63;
    const int wm = (wave >> 1) * 64, wn = (wave & 1) * 64;
    const int q = lane >> 4, c = lane & 15;
    const int srow = lane >> 3;            // 0..7
    const int gch  = (lane & 7) ^ srow;    // swizzled source chunk

    const ushort_t* ag = A + (size_t)(m0 + wave*8 + srow) * 1024 + gch*8;
    const ushort_t* bg = W + (size_t)(n0 + wave*8 + srow) * 1024 + gch*8;
    ushort_t* al = As + wave*512;
    ushort_t* bl = Bs + wave*512;

    for (int k0 = 0; k0 < 1024; k0 += 64) {
        __syncthreads();
#pragma unroll
        for (int n = 0; n < 4; ++n) gld_lds16(ag + (size_t)n*32768 + k0, al + n*2048);
#pragma unroll
        for (int n = 0; n < 4; ++n) gld_lds16(bg + (size_t)n*32768 + k0, bl + n*2048);
        asm volatile("s_waitcnt vmcnt(0)" ::: "memory");
        __syncthreads();

#pragma unroll
        for (int sk = 0; sk < 2; ++sk) {
            short8 af[4], bf[4];
#pragma unroll
            for (int i = 0; i < 4; ++i) {
                int row = wm + i*16 + c;
                af[i] = *(const short8*)(As + row*64 + (((sk*4 + q) ^ (row & 7)) * 8));
            }
#pragma unroll
            for (int j = 0; j < 4; ++j) {
                int row = wn + j*16 + c;
                bf[j] = *(const short8*)(Bs + row*64 + (((sk*4 + q) ^ (row & 7)) * 8));
            }
#pragma unroll
            for (int i = 0; i < 4; ++i)
#pragma unroll
                for (int j = 0; j < 4; ++j)
                    acc[i][j] = __builtin_amdgcn_mfma_f32_16x16x32_bf16(af[i], bf[j], acc[i][j], 0, 0, 0);
        }
    }
}

// ---------------- GEMM core B (pipelined; used by the 1-round gemm_out):
// BM=256 BN=128 BK=64, 8 waves, 3-deep LDS ring, counted vmcnt(6).
__device__ __forceinline__ void gemm_pipe256(const ushort_t* __restrict__ A,
                                             const ushort_t* __restrict__ W,
                                             ushort_t* __restrict__ As,   // 3*16384
                                             ushort_t* __restrict__ Bs,   // 3*8192
                                             int m0, int n0, f32x4 (&acc)[4][4]) {
    const int tid  = threadIdx.x;
    const int wave = tid >> 6, lane = tid & 63;
    const int wm = (wave >> 1) * 64, wn = (wave & 1) * 64;
    const int q = lane >> 4, c = lane & 15;
    const int srow = lane >> 3;            // 0..7
    const int gch  = (lane & 7) ^ srow;    // swizzled source chunk

    const ushort_t* ag = A + (size_t)(m0 + wave * 8 + srow) * 1024 + gch * 8;
    const ushort_t* bg = W + (size_t)(n0 + wave * 8 + srow) * 1024 + gch * 8;
    ushort_t* adst = As + wave * 512;
    ushort_t* bdst = Bs + wave * 512;

    // prologue: stage tile0 -> buf0, tile1 -> buf1 (6 loads each, per thread)
#pragma unroll
    for (int n = 0; n < 4; ++n) gld_lds16(ag + (size_t)n * 65536,      adst + n * 4096);
#pragma unroll
    for (int n = 0; n < 2; ++n) gld_lds16(bg + (size_t)n * 65536,      bdst + n * 4096);
#pragma unroll
    for (int n = 0; n < 4; ++n) gld_lds16(ag + (size_t)n * 65536 + 64, adst + 16384 + n * 4096);
#pragma unroll
    for (int n = 0; n < 2; ++n) gld_lds16(bg + (size_t)n * 65536 + 64, bdst + 8192 + n * 4096);
    asm volatile("s_waitcnt vmcnt(6)" ::: "memory");   // tile0 landed; tile1 in flight
    __builtin_amdgcn_s_barrier();

    const int ch0 = (q ^ (c & 7)) * 8;
    const int ch1 = ((4 + q) ^ (c & 7)) * 8;
    int cur = 0;
    for (int t = 0; t < 16; ++t) {
        const int nx2 = (cur >= 1) ? cur - 1 : 2;          // (t+2)%3
        const ushort_t* ab = As + cur * 16384 + (wm + c) * 64;
        const ushort_t* bb = Bs + cur * 8192  + (wn + c) * 64;
        const int kc = (t + 2) * 64;
        const bool pf = (t < 14);
        short8 af[4], bf[4];

        // ---- phase 0: sk=0 frags, stage A0,A1,B0 of tile t+2
#pragma unroll
        for (int i = 0; i < 4; ++i) af[i] = *(const short8*)(ab + i * 1024 + ch0);
#pragma unroll
        for (int j = 0; j < 4; ++j) bf[j] = *(const short8*)(bb + j * 1024 + ch0);
        if (pf) {
            gld_lds16(ag + kc,           adst + nx2 * 16384);
            gld_lds16(ag + 65536 + kc,   adst + nx2 * 16384 + 4096);
            gld_lds16(bg + kc,           bdst + nx2 * 8192);
        }
        __builtin_amdgcn_s_barrier();
        asm volatile("s_waitcnt lgkmcnt(0)" ::: "memory");
        __builtin_amdgcn_s_setprio(1);
#pragma unroll
        for (int i = 0; i < 4; ++i)
#pragma unroll
            for (int j = 0; j < 4; ++j)
                acc[i][j] = __builtin_amdgcn_mfma_f32_16x16x32_bf16(af[i], bf[j], acc[i][j], 0, 0, 0);
        __builtin_amdgcn_s_setprio(0);
        __builtin_amdgcn_s_barrier();

        // ---- phase 1: sk=1 frags, stage A2,A3,B1 of tile t+2
#pragma unroll
        for (int i = 0; i < 4; ++i) af[i] = *(const short8*)(ab + i * 1024 + ch1);
#pragma unroll
        for (int j = 0; j < 4; ++j) bf[j] = *(const short8*)(bb + j * 1024 + ch1);
        if (pf) {
            gld_lds16(ag + 131072 + kc,  adst + nx2 * 16384 + 8192);
            gld_lds16(ag + 196608 + kc,  adst + nx2 * 16384 + 12288);
            gld_lds16(bg + 65536 + kc,   bdst + nx2 * 8192 + 4096);
        }
        __builtin_amdgcn_s_barrier();
        asm volatile("s_waitcnt lgkmcnt(0)" ::: "memory");
        __builtin_amdgcn_s_setprio(1);
#pragma unroll
        for (int i = 0; i < 4; ++i)
#pragma unroll
            for (int j = 0; j < 4; ++j)
                acc[i][j] = __builtin_amdgcn_mfma_f32_16x16x32_bf16(af[i], bf[j], acc[i][j], 0, 0, 0);
        __builtin_amdgcn_s_setprio(0);
        // counted wait: retire tile t+1's 6 loads, leave tile t+2's 6 in flight
        if (pf) { asm volatile("s_waitcnt vmcnt(6)" ::: "memory"); }
        else    { asm volatile("s_waitcnt vmcnt(0)" ::: "memory"); }
        __builtin_amdgcn_s_barrier();
        cur = (cur == 2) ? 0 : cur + 1;
    }
}

// Fused QKV projection as one logical N=3072 GEMM, 1536 blocks (flattened),
// T1 bijective XCD swizzle. RoPE fused via table; K/V written in flash's
// MFMA-fragment-tiled layouts. (R2 version, measured 113 us.)
__global__ __launch_bounds__(256) void gemm_qkv_kernel(
    const ushort_t* __restrict__ X, const ushort_t* __restrict__ Wq,
    const ushort_t* __restrict__ Wk, const ushort_t* __restrict__ Wv,
    const float2* __restrict__ tab,
    ushort_t* __restrict__ Q, ushort_t* __restrict__ Kt, ushort_t* __restrict__ Vt) {
    __shared__ ushort_t As[128*64];
    __shared__ ushort_t Bs[128*64];
    const int orig = blockIdx.x;                 // 0..1535, 1536 % 8 == 0
    const int wg = (orig & 7) * 192 + (orig >> 3);
    const int my = wg / 24;
    const int n24 = wg - my * 24;
    const int which = n24 >> 3;
    const ushort_t* W = (which == 0) ? Wq : (which == 1) ? Wk : Wv;
    const int m0 = my * 128;
    const int nloc0 = (n24 & 7) * 128;           // 0..896 within the selected matrix

    f32x4 acc[4][4];
#pragma unroll
    for (int i = 0; i < 4; ++i)
#pragma unroll
        for (int j = 0; j < 4; ++j) acc[i][j] = zero4();

    gemm_core(X, W, As, Bs, m0, nloc0, acc);

    const int lane = threadIdx.x & 63, wave = threadIdx.x >> 6;
    const int q = lane >> 4, c = lane & 15;
    const int wm = (wave >> 1) * 64, wn = (wave & 1) * 64;
    const float scale = (which == 0) ? 0.18033688011112042f : 1.0f;  // 0.125*log2(e) for Q

#pragma unroll
    for (int i = 0; i < 4; ++i)
#pragma unroll
        for (int j = 0; j < 4; ++j) {
            int nn = nloc0 + wn + j*16 + c;      // col within matrix: h*64+d
            int d = nn & 63, h = nn >> 6;
            int pidx = d >> 1;
            float sgn = (d & 1) ? 1.f : -1.f;
#pragma unroll
            for (int r = 0; r < 4; ++r) {
                int mm = m0 + wm + i*16 + q*4 + r;   // row: b*2048+t
                int b = mm >> 11, t = mm & 2047;
                float val = acc[i][j][r];
                if (which == 0) {      // Q: rope + (B,H,T,64) bf16 row-major
                    float partner = __shfl_xor(val, 1);
                    float2 cs = tab[t * 32 + pidx];
                    val = (val * cs.x + sgn * partner * cs.y) * scale;
                    Q[((size_t)((b << 4) + h) * 2048 + t) * 64 + d] = f2bf(val);
                } else if (which == 1) {  // K: rope + scatter into tiled bf16 layout
                    float partner = __shfl_xor(val, 1);
                    float2 cs = tab[t * 32 + pidx];
                    val = val * cs.x + sgn * partner * cs.y;
                    int kb = t >> 6, jn = (t >> 4) & 3, cc2 = t & 15;
                    int ks2 = d >> 5, qq2 = (d >> 3) & 3, e = d & 7;
                    int lane2 = qq2 * 16 + cc2;
                    Kt[((((size_t)((b << 4) + h) * 32 + kb) * 8 + jn * 2 + ks2) << 9) + lane2 * 8 + e] = f2bf(val);
                } else {               // V: scatter into tiled f16 layout
                    int kb = t >> 6, kl = t & 63;
                    int jn = kl >> 4, qq2 = (kl >> 2) & 3;
                    int e = ((jn & 1) << 2) | (kl & 3);
                    int p = ((d >> 4) << 1) | (jn >> 1);
                    int lane2 = qq2 * 16 + (d & 15);
                    Vt[((((size_t)((b << 4) + h) * 32 + kb) * 8 + p) << 9) + lane2 * 8 + e] = f2h(val);
                }
            }
        }
}

__global__ __launch_bounds__(512) void gemm_out_kernel(
    const ushort_t* __restrict__ A, const ushort_t* __restrict__ Wo,
    float* __restrict__ OUT) {
    __shared__ ushort_t As[3 * 16384];
    __shared__ ushort_t Bs[3 * 8192];
    // 256 blocks (32 m-tiles x 8 n-tiles) = exactly 1/CU, XCD-swizzled
    const int orig = blockIdx.x;
    const int wg = (orig & 7) * 32 + (orig >> 3);
    const int m0 = (wg >> 3) * 256, n0 = (wg & 7) * 128;

    f32x4 acc[4][4];
#pragma unroll
    for (int i = 0; i < 4; ++i)
#pragma unroll
        for (int j = 0; j < 4; ++j) acc[i][j] = zero4();

    gemm_pipe256(A, Wo, As, Bs, m0, n0, acc);

    const int lane = threadIdx.x & 63, wave = threadIdx.x >> 6;
    const int q = lane >> 4, c = lane & 15;
    const int wm = (wave >> 1) * 64, wn = (wave & 1) * 64;
#pragma unroll
    for (int i = 0; i < 4; ++i)
#pragma unroll
        for (int j = 0; j < 4; ++j)
#pragma unroll
            for (int r = 0; r < 4; ++r) {
                int mm = m0 + wm + i*16 + q*4 + r;
                int nn = n0 + wn + j*16 + c;
                OUT[(size_t)mm * 1024 + nn] = acc[i][j][r];
            }
}

// ---------------- Flash attention v7: double-buffered K/V with prefetch-before-
// compute (catalog "minimum 2-phase", T3 recipe). Per tile: issue stage(t+1) ->
// compute(t) -> vmcnt(0)+barrier. Load latency (~200-900cy) that v6 exposed
// serially per tile now hides under QK^T/softmax/PV compute. One barrier/tile
// (was 2). 16 KiB LDS. Barrier count uniform (masked waves take the same path).
__global__ __launch_bounds__(256, 3) void flash_kernel(
    const ushort_t* __restrict__ Q, const ushort_t* __restrict__ Kt,
    const ushort_t* __restrict__ Vt, ushort_t* __restrict__ AO) {
    __shared__ ushort_t Ks[2][4096];   // 64x64 bf16 K tiles, fragment-tiled
    __shared__ ushort_t Vs[2][4096];   // 64x64 f16 V tiles, fragment-tiled
    const int bh = blockIdx.x;
    const int c0 = 15 - blockIdx.y;             // LPT: big chunks first
    const int w  = threadIdx.x >> 6, lane = threadIdx.x & 63;
    const int q = lane >> 4, c = lane & 15;
    const int qlo = c0 * 128;
    const int nt  = 2 * c0 + 2;                 // 64-key tiles
    const int wq0 = qlo + w * 32;               // this wave's first query
    const int b = bh >> 4, hh = bh & 15;

    const ushort_t* Qp = Q + (size_t)bh * 131072;
    const ushort_t* kt0 = Kt + (size_t)bh * 131072;
    const ushort_t* vt0 = Vt + (size_t)bh * 131072;

    short8 qf[2][2];
#pragma unroll
    for (int m = 0; m < 2; ++m)
#pragma unroll
        for (int ks = 0; ks < 2; ++ks)
            qf[m][ks] = *(const short8*)(Qp + (size_t)(wq0 + m*16 + c) * 64 + ks * 32 + q * 8);

    f32x4 ot[2][4];
#pragma unroll
    for (int m = 0; m < 2; ++m)
#pragma unroll
        for (int dj = 0; dj < 4; ++dj) ot[m][dj] = zero4();
    float lpart[2] = {0.f, 0.f};

    // prologue: stage tile 0 -> buf 0
#pragma unroll
    for (int s = 0; s < 2; ++s) {
        gld_lds16(kt0 + (s*4 + w)*512 + lane*8, &Ks[0][(s*4 + w)*512]);
        gld_lds16(vt0 + (s*4 + w)*512 + lane*8, &Vs[0][(s*4 + w)*512]);
    }
    asm volatile("s_waitcnt vmcnt(0)" ::: "memory");
    __syncthreads();

    for (int kb = 0; kb < nt; ++kb) {
        const int cur = kb & 1;
        // ---- issue next tile's stage FIRST: latency hides under this tile's compute
        if (kb + 1 < nt) {
            const ushort_t* kt = kt0 + (size_t)(kb + 1) * 4096;
            const ushort_t* vt = vt0 + (size_t)(kb + 1) * 4096;
#pragma unroll
            for (int s = 0; s < 2; ++s) {
                gld_lds16(kt + (s*4 + w)*512 + lane*8, &Ks[cur ^ 1][(s*4 + w)*512]);
                gld_lds16(vt + (s*4 + w)*512 + lane*8, &Vs[cur ^ 1][(s*4 + w)*512]);
            }
        }

        if (kb * 64 <= wq0 + 31) {              // not fully masked for this wave
            const ushort_t* Kb = &Ks[cur][0];
            const ushort_t* Vb = &Vs[cur][0];
            // ---- S^T = K Q^T : row=key(q*4+r), col=query(c)
            f32x4 st[2][4];
#pragma unroll
            for (int jn = 0; jn < 4; ++jn) {
                short8 kf0 = *(const short8*)(Kb + (jn*2+0)*512 + lane*8);
                short8 kf1 = *(const short8*)(Kb + (jn*2+1)*512 + lane*8);
#pragma unroll
                for (int m = 0; m < 2; ++m) {
                    f32x4 t0 = __builtin_amdgcn_mfma_f32_16x16x32_bf16(kf0, qf[m][0], zero4(), 0, 0, 0);
                    st[m][jn] = __builtin_amdgcn_mfma_f32_16x16x32_bf16(kf1, qf[m][1], t0, 0, 0, 0);
                }
            }
            if (kb * 64 + 63 > wq0) {           // partial (diagonal) tile: mask
#pragma unroll
                for (int m = 0; m < 2; ++m) {
                    int query = wq0 + m * 16 + c;
#pragma unroll
                    for (int jn = 0; jn < 4; ++jn)
#pragma unroll
                        for (int r = 0; r < 4; ++r)
                            if (kb * 64 + jn * 16 + q * 4 + r > query) st[m][jn][r] = -1e30f;
                }
            }
            // ---- p = exp2(s'); per-lane l partials; pack f16 B-frags
            half4 pa[2][4];
#pragma unroll
            for (int m = 0; m < 2; ++m)
#pragma unroll
                for (int jn = 0; jn < 4; ++jn) {
                    float p0 = exp2f(st[m][jn][0]), p1 = exp2f(st[m][jn][1]);
                    float p2 = exp2f(st[m][jn][2]), p3 = exp2f(st[m][jn][3]);
                    lpart[m] += (p0 + p1) + (p2 + p3);
                    pa[m][jn] = pk4(p0, p1, p2, p3);
                }
            // ---- O^T += V^T P^T
#pragma unroll
            for (int jnp = 0; jnp < 2; ++jnp)
#pragma unroll
                for (int dj = 0; dj < 4; ++dj) {
                    half4x2 vv = __builtin_bit_cast(half4x2,
                        *(const short8*)(Vb + (dj*2 + jnp)*512 + lane*8));
#pragma unroll
                    for (int m = 0; m < 2; ++m) {
                        ot[m][dj] = __builtin_amdgcn_mfma_f32_16x16x16f16(vv.lo, pa[m][2*jnp],   ot[m][dj], 0, 0, 0);
                        ot[m][dj] = __builtin_amdgcn_mfma_f32_16x16x16f16(vv.hi, pa[m][2*jnp+1], ot[m][dj], 0, 0, 0);
                    }
                }
        }

        // next tile landed + all waves done reading buf[cur^1] (writes target it next iter)
        asm volatile("s_waitcnt vmcnt(0)" ::: "memory");
        __syncthreads();
    }

    // ---- epilogue: quad-reduce l (keys on lanes c,c+16,c+32,c+48), normalize, store
#pragma unroll
    for (int m = 0; m < 2; ++m) {
        float l = lpart[m];
        l += __shfl_xor(l, 16);
        l += __shfl_xor(l, 32);
        float inv = 1.f / l;
        int t = wq0 + m * 16 + c;
        ushort_t* base = AO + ((size_t)b * 2048 + t) * 1024 + hh * 64;
#pragma unroll
        for (int dj = 0; dj < 4; ++dj) {
            ushort4 o;
            o.x = f2bf(ot[m][dj][0] * inv);
            o.y = f2bf(ot[m][dj][1] * inv);
            o.z = f2bf(ot[m][dj][2] * inv);
            o.w = f2bf(ot[m][dj][3] * inv);
            *(ushort4*)(base + dj * 16 + q * 4) = o;
        }
    }
}

extern "C" void kernel_launch(void* const* d_in, const int* in_sizes, int n_in,
                              void* d_out, int out_size, void* d_ws, size_t ws_size,
                              hipStream_t stream) {
    const float* x  = (const float*)d_in[0];
    const float* Wq = (const float*)d_in[2];
    const float* Wk = (const float*)d_in[3];
    const float* Wv = (const float*)d_in[4];
    const float* Wo = (const float*)d_in[5];
    float* out = (float*)d_out;

    ushort_t* ws  = (ushort_t*)d_ws;
    ushort_t* Xb  = ws;                 // 8192x1024 bf16; reused as AO after projections
    ushort_t* Qb  = ws + 8388608;
    ushort_t* Ktb = ws + 16777216;      // bf16, MFMA-fragment-tiled (bh,kb,p,lane,8)
    ushort_t* Vtb = ws + 25165824;      // f16,  MFMA-fragment-tiled (bh,kb,p,lane,8)
    ushort_t* Wqb = ws + 33554432;
    ushort_t* Wkb = Wqb + 1048576;
    ushort_t* Wvb = Wkb + 1048576;
    ushort_t* Wob = Wvb + 1048576;
    float2*   tab = (float2*)(ws + 37748736);   // 512 KB rope table

    cvt_all<<<12544, 256, 0, stream>>>(x, Wq, Wk, Wv, Wo, Xb, Wqb, Wkb, Wvb, Wob, tab);

    // fused QKV: one logical N=3072 GEMM; 128x128 proven core + XCD swizzle
    gemm_qkv_kernel<<<1536, 256, 0, stream>>>(Xb, Wqb, Wkb, Wvb, tab, Qb, Ktb, Vtb);

    flash_kernel<<<dim3(64, 16), 256, 0, stream>>>(Qb, Ktb, Vtb, Xb);

    gemm_out_kernel<<<256, 512, 0, stream>>>(Xb, Wob, out);
}

// Round 5
// 284.342 us; speedup vs baseline: 1.1455x; 1.0165x over previous
//
#include <hip/hip_runtime.h>
#include <cstdint>
#include <cstddef>

typedef unsigned short ushort_t;
typedef __attribute__((ext_vector_type(8))) short short8;
typedef __attribute__((ext_vector_type(4))) float f32x4;
typedef __attribute__((ext_vector_type(4))) _Float16 half4;
typedef __attribute__((ext_vector_type(8))) _Float16 half8;
typedef __attribute__((ext_vector_type(2))) _Float16 half2;
typedef __attribute__((ext_vector_type(2))) __fp16 fp16v2;
struct half4x2 { half4 lo, hi; };
struct half2x2 { half2 lo, hi; };

__device__ __forceinline__ unsigned short f2bf(float f) {
    unsigned u = __float_as_uint(f);
    u += 0x7fffu + ((u >> 16) & 1u);
    return (unsigned short)(u >> 16);
}
__device__ __forceinline__ float bf2f(unsigned short h) {
    return __uint_as_float((unsigned)h << 16);
}
__device__ __forceinline__ ushort_t f2h(float f) {
    _Float16 h = (_Float16)f;
    return __builtin_bit_cast(unsigned short, h);
}
__device__ __forceinline__ f32x4 zero4() {
    f32x4 z; z[0]=0.f; z[1]=0.f; z[2]=0.f; z[3]=0.f; return z;
}
__device__ __forceinline__ half4 pk4(float a, float b, float cc, float d) {
    half2x2 t;
    t.lo = __builtin_bit_cast(half2, (fp16v2)__builtin_amdgcn_cvt_pkrtz(a, b));
    t.hi = __builtin_bit_cast(half2, (fp16v2)__builtin_amdgcn_cvt_pkrtz(cc, d));
    return __builtin_bit_cast(half4, t);
}
__device__ __forceinline__ void gld_lds16(const ushort_t* g, ushort_t* l) {
    __builtin_amdgcn_global_load_lds(
        (const __attribute__((address_space(1))) void*)g,
        (__attribute__((address_space(3))) void*)l, 16, 0, 0);
}

// ---------------- fused fp32->bf16 convert (x + 4 weights) + rope table, one launch ----------------
__global__ void cvt_all(const float* __restrict__ x,
                        const float* __restrict__ wq, const float* __restrict__ wk,
                        const float* __restrict__ wv, const float* __restrict__ wo,
                        ushort_t* __restrict__ xb,
                        ushort_t* __restrict__ wqb, ushort_t* __restrict__ wkb,
                        ushort_t* __restrict__ wvb, ushort_t* __restrict__ wob,
                        float2* __restrict__ tab) {
    int idx = blockIdx.x * 256 + threadIdx.x;   // grid 12544 blocks exactly
    if (idx >= 3145728) {                        // rope table: 65536 entries
        int i = idx - 3145728;
        int t = i >> 5, p = i & 31;
        float freq = __expf((float)p * -0.2878231366242557f);  // 10000^(-p/32)
        float sn, cs;
        sincosf((float)t * freq, &sn, &cs);
        tab[i] = make_float2(cs, sn);
        return;
    }
    const float* src; ushort_t* dst; int off;
    if (idx < 2097152) { src = x; dst = xb; off = idx; }
    else {
        int r = idx - 2097152;
        int w = r >> 18;
        off = r & 262143;
        src = (w == 0) ? wq : (w == 1) ? wk : (w == 2) ? wv : wo;
        dst = (w == 0) ? wqb : (w == 1) ? wkb : (w == 2) ? wvb : wob;
    }
    float4 v = ((const float4*)src)[off];
    ushort_t o[4];
    o[0] = f2bf(v.x); o[1] = f2bf(v.y); o[2] = f2bf(v.z); o[3] = f2bf(v.w);
    *(ushort4*)(dst + 4*(size_t)off) = *(const ushort4*)o;
}

// ---------------- GEMM core A (proven 113 us on qkv): BM=BN=128, BK=64, 4 waves,
// 32 KiB LDS -> multi-block/CU co-residency hides the barrier drain (m114).
// XOR-swizzled LDS, C = A(Mx1024) W(Nx1024)^T.
__device__ __forceinline__ void gemm_core(const ushort_t* __restrict__ A,
                                          const ushort_t* __restrict__ W,
                                          ushort_t* As, ushort_t* Bs,
                                          int m0, int n0, f32x4 (&acc)[4][4]) {
    const int tid  = threadIdx.x;
    const int wave = tid >> 6, lane = tid & 63;
    const int wm = (wave >> 1) * 64, wn = (wave & 1) * 64;
    const int q = lane >> 4, c = lane & 15;
    const int srow = lane >> 3;            // 0..7
    const int gch  = (lane & 7) ^ srow;    // swizzled source chunk

    const ushort_t* ag = A + (size_t)(m0 + wave*8 + srow) * 1024 + gch*8;
    const ushort_t* bg = W + (size_t)(n0 + wave*8 + srow) * 1024 + gch*8;
    ushort_t* al = As + wave*512;
    ushort_t* bl = Bs + wave*512;

    for (int k0 = 0; k0 < 1024; k0 += 64) {
        __syncthreads();
#pragma unroll
        for (int n = 0; n < 4; ++n) gld_lds16(ag + (size_t)n*32768 + k0, al + n*2048);
#pragma unroll
        for (int n = 0; n < 4; ++n) gld_lds16(bg + (size_t)n*32768 + k0, bl + n*2048);
        asm volatile("s_waitcnt vmcnt(0)" ::: "memory");
        __syncthreads();

#pragma unroll
        for (int sk = 0; sk < 2; ++sk) {
            short8 af[4], bf[4];
#pragma unroll
            for (int i = 0; i < 4; ++i) {
                int row = wm + i*16 + c;
                af[i] = *(const short8*)(As + row*64 + (((sk*4 + q) ^ (row & 7)) * 8));
            }
#pragma unroll
            for (int j = 0; j < 4; ++j) {
                int row = wn + j*16 + c;
                bf[j] = *(const short8*)(Bs + row*64 + (((sk*4 + q) ^ (row & 7)) * 8));
            }
#pragma unroll
            for (int i = 0; i < 4; ++i)
#pragma unroll
                for (int j = 0; j < 4; ++j)
                    acc[i][j] = __builtin_amdgcn_mfma_f32_16x16x32_bf16(af[i], bf[j], acc[i][j], 0, 0, 0);
        }
    }
}

// ---------------- GEMM core B (pipelined; used by the 1-round gemm_out):
// BM=256 BN=128 BK=64, 8 waves, 3-deep LDS ring, counted vmcnt(6).
__device__ __forceinline__ void gemm_pipe256(const ushort_t* __restrict__ A,
                                             const ushort_t* __restrict__ W,
                                             ushort_t* __restrict__ As,   // 3*16384
                                             ushort_t* __restrict__ Bs,   // 3*8192
                                             int m0, int n0, f32x4 (&acc)[4][4]) {
    const int tid  = threadIdx.x;
    const int wave = tid >> 6, lane = tid & 63;
    const int wm = (wave >> 1) * 64, wn = (wave & 1) * 64;
    const int q = lane >> 4, c = lane & 15;
    const int srow = lane >> 3;            // 0..7
    const int gch  = (lane & 7) ^ srow;    // swizzled source chunk

    const ushort_t* ag = A + (size_t)(m0 + wave * 8 + srow) * 1024 + gch * 8;
    const ushort_t* bg = W + (size_t)(n0 + wave * 8 + srow) * 1024 + gch * 8;
    ushort_t* adst = As + wave * 512;
    ushort_t* bdst = Bs + wave * 512;

    // prologue: stage tile0 -> buf0, tile1 -> buf1 (6 loads each, per thread)
#pragma unroll
    for (int n = 0; n < 4; ++n) gld_lds16(ag + (size_t)n * 65536,      adst + n * 4096);
#pragma unroll
    for (int n = 0; n < 2; ++n) gld_lds16(bg + (size_t)n * 65536,      bdst + n * 4096);
#pragma unroll
    for (int n = 0; n < 4; ++n) gld_lds16(ag + (size_t)n * 65536 + 64, adst + 16384 + n * 4096);
#pragma unroll
    for (int n = 0; n < 2; ++n) gld_lds16(bg + (size_t)n * 65536 + 64, bdst + 8192 + n * 4096);
    asm volatile("s_waitcnt vmcnt(6)" ::: "memory");   // tile0 landed; tile1 in flight
    __builtin_amdgcn_s_barrier();

    const int ch0 = (q ^ (c & 7)) * 8;
    const int ch1 = ((4 + q) ^ (c & 7)) * 8;
    int cur = 0;
    for (int t = 0; t < 16; ++t) {
        const int nx2 = (cur >= 1) ? cur - 1 : 2;          // (t+2)%3
        const ushort_t* ab = As + cur * 16384 + (wm + c) * 64;
        const ushort_t* bb = Bs + cur * 8192  + (wn + c) * 64;
        const int kc = (t + 2) * 64;
        const bool pf = (t < 14);
        short8 af[4], bf[4];

        // ---- phase 0: sk=0 frags, stage A0,A1,B0 of tile t+2
#pragma unroll
        for (int i = 0; i < 4; ++i) af[i] = *(const short8*)(ab + i * 1024 + ch0);
#pragma unroll
        for (int j = 0; j < 4; ++j) bf[j] = *(const short8*)(bb + j * 1024 + ch0);
        if (pf) {
            gld_lds16(ag + kc,           adst + nx2 * 16384);
            gld_lds16(ag + 65536 + kc,   adst + nx2 * 16384 + 4096);
            gld_lds16(bg + kc,           bdst + nx2 * 8192);
        }
        __builtin_amdgcn_s_barrier();
        asm volatile("s_waitcnt lgkmcnt(0)" ::: "memory");
        __builtin_amdgcn_s_setprio(1);
#pragma unroll
        for (int i = 0; i < 4; ++i)
#pragma unroll
            for (int j = 0; j < 4; ++j)
                acc[i][j] = __builtin_amdgcn_mfma_f32_16x16x32_bf16(af[i], bf[j], acc[i][j], 0, 0, 0);
        __builtin_amdgcn_s_setprio(0);
        __builtin_amdgcn_s_barrier();

        // ---- phase 1: sk=1 frags, stage A2,A3,B1 of tile t+2
#pragma unroll
        for (int i = 0; i < 4; ++i) af[i] = *(const short8*)(ab + i * 1024 + ch1);
#pragma unroll
        for (int j = 0; j < 4; ++j) bf[j] = *(const short8*)(bb + j * 1024 + ch1);
        if (pf) {
            gld_lds16(ag + 131072 + kc,  adst + nx2 * 16384 + 8192);
            gld_lds16(ag + 196608 + kc,  adst + nx2 * 16384 + 12288);
            gld_lds16(bg + 65536 + kc,   bdst + nx2 * 8192 + 4096);
        }
        __builtin_amdgcn_s_barrier();
        asm volatile("s_waitcnt lgkmcnt(0)" ::: "memory");
        __builtin_amdgcn_s_setprio(1);
#pragma unroll
        for (int i = 0; i < 4; ++i)
#pragma unroll
            for (int j = 0; j < 4; ++j)
                acc[i][j] = __builtin_amdgcn_mfma_f32_16x16x32_bf16(af[i], bf[j], acc[i][j], 0, 0, 0);
        __builtin_amdgcn_s_setprio(0);
        // counted wait: retire tile t+1's 6 loads, leave tile t+2's 6 in flight
        if (pf) { asm volatile("s_waitcnt vmcnt(6)" ::: "memory"); }
        else    { asm volatile("s_waitcnt vmcnt(0)" ::: "memory"); }
        __builtin_amdgcn_s_barrier();
        cur = (cur == 2) ? 0 : cur + 1;
    }
}

// Fused QKV projection as one logical N=3072 GEMM, 1536 blocks (flattened),
// T1 bijective XCD swizzle. RoPE fused via table; K/V written in flash's
// MFMA-fragment-tiled layouts. (R2 version, measured 113 us x3.)
__global__ __launch_bounds__(256) void gemm_qkv_kernel(
    const ushort_t* __restrict__ X, const ushort_t* __restrict__ Wq,
    const ushort_t* __restrict__ Wk, const ushort_t* __restrict__ Wv,
    const float2* __restrict__ tab,
    ushort_t* __restrict__ Q, ushort_t* __restrict__ Kt, ushort_t* __restrict__ Vt) {
    __shared__ ushort_t As[128*64];
    __shared__ ushort_t Bs[128*64];
    const int orig = blockIdx.x;                 // 0..1535, 1536 % 8 == 0
    const int wg = (orig & 7) * 192 + (orig >> 3);
    const int my = wg / 24;
    const int n24 = wg - my * 24;
    const int which = n24 >> 3;
    const ushort_t* W = (which == 0) ? Wq : (which == 1) ? Wk : Wv;
    const int m0 = my * 128;
    const int nloc0 = (n24 & 7) * 128;           // 0..896 within the selected matrix

    f32x4 acc[4][4];
#pragma unroll
    for (int i = 0; i < 4; ++i)
#pragma unroll
        for (int j = 0; j < 4; ++j) acc[i][j] = zero4();

    gemm_core(X, W, As, Bs, m0, nloc0, acc);

    const int lane = threadIdx.x & 63, wave = threadIdx.x >> 6;
    const int q = lane >> 4, c = lane & 15;
    const int wm = (wave >> 1) * 64, wn = (wave & 1) * 64;
    const float scale = (which == 0) ? 0.18033688011112042f : 1.0f;  // 0.125*log2(e) for Q

#pragma unroll
    for (int i = 0; i < 4; ++i)
#pragma unroll
        for (int j = 0; j < 4; ++j) {
            int nn = nloc0 + wn + j*16 + c;      // col within matrix: h*64+d
            int d = nn & 63, h = nn >> 6;
            int pidx = d >> 1;
            float sgn = (d & 1) ? 1.f : -1.f;
#pragma unroll
            for (int r = 0; r < 4; ++r) {
                int mm = m0 + wm + i*16 + q*4 + r;   // row: b*2048+t
                int b = mm >> 11, t = mm & 2047;
                float val = acc[i][j][r];
                if (which == 0) {      // Q: rope + (B,H,T,64) bf16 row-major
                    float partner = __shfl_xor(val, 1);
                    float2 cs = tab[t * 32 + pidx];
                    val = (val * cs.x + sgn * partner * cs.y) * scale;
                    Q[((size_t)((b << 4) + h) * 2048 + t) * 64 + d] = f2bf(val);
                } else if (which == 1) {  // K: rope + scatter into tiled bf16 layout
                    float partner = __shfl_xor(val, 1);
                    float2 cs = tab[t * 32 + pidx];
                    val = val * cs.x + sgn * partner * cs.y;
                    int kb = t >> 6, jn = (t >> 4) & 3, cc2 = t & 15;
                    int ks2 = d >> 5, qq2 = (d >> 3) & 3, e = d & 7;
                    int lane2 = qq2 * 16 + cc2;
                    Kt[((((size_t)((b << 4) + h) * 32 + kb) * 8 + jn * 2 + ks2) << 9) + lane2 * 8 + e] = f2bf(val);
                } else {               // V: scatter into tiled f16 layout
                    int kb = t >> 6, kl = t & 63;
                    int jn = kl >> 4, qq2 = (kl >> 2) & 3;
                    int e = ((jn & 1) << 2) | (kl & 3);
                    int p = ((d >> 4) << 1) | (jn >> 1);
                    int lane2 = qq2 * 16 + (d & 15);
                    Vt[((((size_t)((b << 4) + h) * 32 + kb) * 8 + p) << 9) + lane2 * 8 + e] = f2h(val);
                }
            }
        }
}

__global__ __launch_bounds__(512) void gemm_out_kernel(
    const ushort_t* __restrict__ A, const ushort_t* __restrict__ Wo,
    float* __restrict__ OUT) {
    __shared__ ushort_t As[3 * 16384];
    __shared__ ushort_t Bs[3 * 8192];
    // 256 blocks (32 m-tiles x 8 n-tiles) = exactly 1/CU, XCD-swizzled
    const int orig = blockIdx.x;
    const int wg = (orig & 7) * 32 + (orig >> 3);
    const int m0 = (wg >> 3) * 256, n0 = (wg & 7) * 128;

    f32x4 acc[4][4];
#pragma unroll
    for (int i = 0; i < 4; ++i)
#pragma unroll
        for (int j = 0; j < 4; ++j) acc[i][j] = zero4();

    gemm_pipe256(A, Wo, As, Bs, m0, n0, acc);

    const int lane = threadIdx.x & 63, wave = threadIdx.x >> 6;
    const int q = lane >> 4, c = lane & 15;
    const int wm = (wave >> 1) * 64, wn = (wave & 1) * 64;
#pragma unroll
    for (int i = 0; i < 4; ++i)
#pragma unroll
        for (int j = 0; j < 4; ++j)
#pragma unroll
            for (int r = 0; r < 4; ++r) {
                int mm = m0 + wm + i*16 + q*4 + r;
                int nn = n0 + wn + j*16 + c;
                OUT[(size_t)mm * 1024 + nn] = acc[i][j][r];
            }
}

// ---------------- Flash attention v8: v7 + PV fused to mfma_f32_16x16x32_f16.
// Two x16 PV MFMAs (vv.lo*pa[2j] + vv.hi*pa[2j+1]) == one x32 MFMA on the
// concatenated operands (positional k-pairing is preserved by concatenation on
// BOTH operands). Halves PV matrix-pipe cycles and the ot dependency chain.
__global__ __launch_bounds__(256, 3) void flash_kernel(
    const ushort_t* __restrict__ Q, const ushort_t* __restrict__ Kt,
    const ushort_t* __restrict__ Vt, ushort_t* __restrict__ AO) {
    __shared__ ushort_t Ks[2][4096];   // 64x64 bf16 K tiles, fragment-tiled
    __shared__ ushort_t Vs[2][4096];   // 64x64 f16 V tiles, fragment-tiled
    const int bh = blockIdx.x;
    const int c0 = 15 - blockIdx.y;             // LPT: big chunks first
    const int w  = threadIdx.x >> 6, lane = threadIdx.x & 63;
    const int q = lane >> 4, c = lane & 15;
    const int qlo = c0 * 128;
    const int nt  = 2 * c0 + 2;                 // 64-key tiles
    const int wq0 = qlo + w * 32;               // this wave's first query
    const int b = bh >> 4, hh = bh & 15;

    const ushort_t* Qp = Q + (size_t)bh * 131072;
    const ushort_t* kt0 = Kt + (size_t)bh * 131072;
    const ushort_t* vt0 = Vt + (size_t)bh * 131072;

    short8 qf[2][2];
#pragma unroll
    for (int m = 0; m < 2; ++m)
#pragma unroll
        for (int ks = 0; ks < 2; ++ks)
            qf[m][ks] = *(const short8*)(Qp + (size_t)(wq0 + m*16 + c) * 64 + ks * 32 + q * 8);

    f32x4 ot[2][4];
#pragma unroll
    for (int m = 0; m < 2; ++m)
#pragma unroll
        for (int dj = 0; dj < 4; ++dj) ot[m][dj] = zero4();
    float lpart[2] = {0.f, 0.f};

    // prologue: stage tile 0 -> buf 0
#pragma unroll
    for (int s = 0; s < 2; ++s) {
        gld_lds16(kt0 + (s*4 + w)*512 + lane*8, &Ks[0][(s*4 + w)*512]);
        gld_lds16(vt0 + (s*4 + w)*512 + lane*8, &Vs[0][(s*4 + w)*512]);
    }
    asm volatile("s_waitcnt vmcnt(0)" ::: "memory");
    __syncthreads();

    for (int kb = 0; kb < nt; ++kb) {
        const int cur = kb & 1;
        // ---- issue next tile's stage FIRST: latency hides under this tile's compute
        if (kb + 1 < nt) {
            const ushort_t* kt = kt0 + (size_t)(kb + 1) * 4096;
            const ushort_t* vt = vt0 + (size_t)(kb + 1) * 4096;
#pragma unroll
            for (int s = 0; s < 2; ++s) {
                gld_lds16(kt + (s*4 + w)*512 + lane*8, &Ks[cur ^ 1][(s*4 + w)*512]);
                gld_lds16(vt + (s*4 + w)*512 + lane*8, &Vs[cur ^ 1][(s*4 + w)*512]);
            }
        }

        if (kb * 64 <= wq0 + 31) {              // not fully masked for this wave
            const ushort_t* Kb = &Ks[cur][0];
            const ushort_t* Vb = &Vs[cur][0];
            // ---- S^T = K Q^T : row=key(q*4+r), col=query(c)
            f32x4 st[2][4];
#pragma unroll
            for (int jn = 0; jn < 4; ++jn) {
                short8 kf0 = *(const short8*)(Kb + (jn*2+0)*512 + lane*8);
                short8 kf1 = *(const short8*)(Kb + (jn*2+1)*512 + lane*8);
#pragma unroll
                for (int m = 0; m < 2; ++m) {
                    f32x4 t0 = __builtin_amdgcn_mfma_f32_16x16x32_bf16(kf0, qf[m][0], zero4(), 0, 0, 0);
                    st[m][jn] = __builtin_amdgcn_mfma_f32_16x16x32_bf16(kf1, qf[m][1], t0, 0, 0, 0);
                }
            }
            if (kb * 64 + 63 > wq0) {           // partial (diagonal) tile: mask
#pragma unroll
                for (int m = 0; m < 2; ++m) {
                    int query = wq0 + m * 16 + c;
#pragma unroll
                    for (int jn = 0; jn < 4; ++jn)
#pragma unroll
                        for (int r = 0; r < 4; ++r)
                            if (kb * 64 + jn * 16 + q * 4 + r > query) st[m][jn][r] = -1e30f;
                }
            }
            // ---- p = exp2(s'); per-lane l partials; pack f16 B-frags
            half4 pa[2][4];
#pragma unroll
            for (int m = 0; m < 2; ++m)
#pragma unroll
                for (int jn = 0; jn < 4; ++jn) {
                    float p0 = exp2f(st[m][jn][0]), p1 = exp2f(st[m][jn][1]);
                    float p2 = exp2f(st[m][jn][2]), p3 = exp2f(st[m][jn][3]);
                    lpart[m] += (p0 + p1) + (p2 + p3);
                    pa[m][jn] = pk4(p0, p1, p2, p3);
                }
            // ---- O^T += V^T P^T  (fused x32: one MFMA per (jnp,dj,m))
#pragma unroll
            for (int jnp = 0; jnp < 2; ++jnp)
#pragma unroll
                for (int dj = 0; dj < 4; ++dj) {
                    half8 vv8 = __builtin_bit_cast(half8,
                        *(const short8*)(Vb + (dj*2 + jnp)*512 + lane*8));
#pragma unroll
                    for (int m = 0; m < 2; ++m) {
                        half4x2 pb;
                        pb.lo = pa[m][2*jnp];
                        pb.hi = pa[m][2*jnp+1];
                        ot[m][dj] = __builtin_amdgcn_mfma_f32_16x16x32_f16(
                            vv8, __builtin_bit_cast(half8, pb), ot[m][dj], 0, 0, 0);
                    }
                }
        }

        // next tile landed + all waves done reading buf[cur^1] (writes target it next iter)
        asm volatile("s_waitcnt vmcnt(0)" ::: "memory");
        __syncthreads();
    }

    // ---- epilogue: quad-reduce l (keys on lanes c,c+16,c+32,c+48), normalize, store
#pragma unroll
    for (int m = 0; m < 2; ++m) {
        float l = lpart[m];
        l += __shfl_xor(l, 16);
        l += __shfl_xor(l, 32);
        float inv = 1.f / l;
        int t = wq0 + m * 16 + c;
        ushort_t* base = AO + ((size_t)b * 2048 + t) * 1024 + hh * 64;
#pragma unroll
        for (int dj = 0; dj < 4; ++dj) {
            ushort4 o;
            o.x = f2bf(ot[m][dj][0] * inv);
            o.y = f2bf(ot[m][dj][1] * inv);
            o.z = f2bf(ot[m][dj][2] * inv);
            o.w = f2bf(ot[m][dj][3] * inv);
            *(ushort4*)(base + dj * 16 + q * 4) = o;
        }
    }
}

extern "C" void kernel_launch(void* const* d_in, const int* in_sizes, int n_in,
                              void* d_out, int out_size, void* d_ws, size_t ws_size,
                              hipStream_t stream) {
    const float* x  = (const float*)d_in[0];
    const float* Wq = (const float*)d_in[2];
    const float* Wk = (const float*)d_in[3];
    const float* Wv = (const float*)d_in[4];
    const float* Wo = (const float*)d_in[5];
    float* out = (float*)d_out;

    ushort_t* ws  = (ushort_t*)d_ws;
    ushort_t* Xb  = ws;                 // 8192x1024 bf16; reused as AO after projections
    ushort_t* Qb  = ws + 8388608;
    ushort_t* Ktb = ws + 16777216;      // bf16, MFMA-fragment-tiled (bh,kb,p,lane,8)
    ushort_t* Vtb = ws + 25165824;      // f16,  MFMA-fragment-tiled (bh,kb,p,lane,8)
    ushort_t* Wqb = ws + 33554432;
    ushort_t* Wkb = Wqb + 1048576;
    ushort_t* Wvb = Wkb + 1048576;
    ushort_t* Wob = Wvb + 1048576;
    float2*   tab = (float2*)(ws + 37748736);   // 512 KB rope table

    cvt_all<<<12544, 256, 0, stream>>>(x, Wq, Wk, Wv, Wo, Xb, Wqb, Wkb, Wvb, Wob, tab);

    // fused QKV: one logical N=3072 GEMM; 128x128 proven core + XCD swizzle
    gemm_qkv_kernel<<<1536, 256, 0, stream>>>(Xb, Wqb, Wkb, Wvb, tab, Qb, Ktb, Vtb);

    flash_kernel<<<dim3(64, 16), 256, 0, stream>>>(Qb, Ktb, Vtb, Xb);

    gemm_out_kernel<<<256, 512, 0, stream>>>(Xb, Wob, out);
}

// Round 6
// 278.466 us; speedup vs baseline: 1.1697x; 1.0211x over previous
//
#include <hip/hip_runtime.h>
#include <cstdint>
#include <cstddef>

typedef unsigned short ushort_t;
typedef __attribute__((ext_vector_type(8))) short short8;
typedef __attribute__((ext_vector_type(4))) float f32x4;
typedef __attribute__((ext_vector_type(4))) _Float16 half4;
typedef __attribute__((ext_vector_type(8))) _Float16 half8;
typedef __attribute__((ext_vector_type(2))) _Float16 half2;
typedef __attribute__((ext_vector_type(2))) __fp16 fp16v2;
struct half4x2 { half4 lo, hi; };
struct half2x2 { half2 lo, hi; };

__device__ __forceinline__ unsigned short f2bf(float f) {
    unsigned u = __float_as_uint(f);
    u += 0x7fffu + ((u >> 16) & 1u);
    return (unsigned short)(u >> 16);
}
__device__ __forceinline__ float bf2f(unsigned short h) {
    return __uint_as_float((unsigned)h << 16);
}
__device__ __forceinline__ ushort_t f2h(float f) {
    _Float16 h = (_Float16)f;
    return __builtin_bit_cast(unsigned short, h);
}
__device__ __forceinline__ f32x4 zero4() {
    f32x4 z; z[0]=0.f; z[1]=0.f; z[2]=0.f; z[3]=0.f; return z;
}
__device__ __forceinline__ half4 pk4(float a, float b, float cc, float d) {
    half2x2 t;
    t.lo = __builtin_bit_cast(half2, (fp16v2)__builtin_amdgcn_cvt_pkrtz(a, b));
    t.hi = __builtin_bit_cast(half2, (fp16v2)__builtin_amdgcn_cvt_pkrtz(cc, d));
    return __builtin_bit_cast(half4, t);
}
__device__ __forceinline__ void gld_lds16(const ushort_t* g, ushort_t* l) {
    __builtin_amdgcn_global_load_lds(
        (const __attribute__((address_space(1))) void*)g,
        (__attribute__((address_space(3))) void*)l, 16, 0, 0);
}

// ---------------- fused fp32->bf16 convert (x + 4 weights) + rope table, one launch ----------------
__global__ void cvt_all(const float* __restrict__ x,
                        const float* __restrict__ wq, const float* __restrict__ wk,
                        const float* __restrict__ wv, const float* __restrict__ wo,
                        ushort_t* __restrict__ xb,
                        ushort_t* __restrict__ wqb, ushort_t* __restrict__ wkb,
                        ushort_t* __restrict__ wvb, ushort_t* __restrict__ wob,
                        float2* __restrict__ tab) {
    int idx = blockIdx.x * 256 + threadIdx.x;   // grid 12544 blocks exactly
    if (idx >= 3145728) {                        // rope table: 65536 entries
        int i = idx - 3145728;
        int t = i >> 5, p = i & 31;
        float freq = __expf((float)p * -0.2878231366242557f);  // 10000^(-p/32)
        float sn, cs;
        sincosf((float)t * freq, &sn, &cs);
        tab[i] = make_float2(cs, sn);
        return;
    }
    const float* src; ushort_t* dst; int off;
    if (idx < 2097152) { src = x; dst = xb; off = idx; }
    else {
        int r = idx - 2097152;
        int w = r >> 18;
        off = r & 262143;
        src = (w == 0) ? wq : (w == 1) ? wk : (w == 2) ? wv : wo;
        dst = (w == 0) ? wqb : (w == 1) ? wkb : (w == 2) ? wvb : wob;
    }
    float4 v = ((const float4*)src)[off];
    ushort_t o[4];
    o[0] = f2bf(v.x); o[1] = f2bf(v.y); o[2] = f2bf(v.z); o[3] = f2bf(v.w);
    *(ushort4*)(dst + 4*(size_t)off) = *(const ushort4*)o;
}

// ---------------- GEMM core A-db: BM=BN=128, BK=64, 4 waves, T3 minimum
// 2-phase: double-buffered LDS (64 KiB), stage(t+1) issued BEFORE compute(t),
// ONE barrier per K-step (its implicit vmcnt(0) drain retires loads that had
// the whole compute to land). XOR-swizzled LDS (bank-conflict 0, proven).
// C = A(Mx1024) W(Nx1024)^T.
__device__ __forceinline__ void gemm_core_db(const ushort_t* __restrict__ A,
                                             const ushort_t* __restrict__ W,
                                             ushort_t* As, ushort_t* Bs,   // each 2*8192
                                             int m0, int n0, f32x4 (&acc)[4][4]) {
    const int tid  = threadIdx.x;
    const int wave = tid >> 6, lane = tid & 63;
    const int wm = (wave >> 1) * 64, wn = (wave & 1) * 64;
    const int q = lane >> 4, c = lane & 15;
    const int srow = lane >> 3;            // 0..7
    const int gch  = (lane & 7) ^ srow;    // swizzled source chunk

    const ushort_t* ag = A + (size_t)(m0 + wave*8 + srow) * 1024 + gch*8;
    const ushort_t* bg = W + (size_t)(n0 + wave*8 + srow) * 1024 + gch*8;
    ushort_t* al = As + wave*512;
    ushort_t* bl = Bs + wave*512;

    // prologue: stage K-step 0 into buffer 0
#pragma unroll
    for (int n = 0; n < 4; ++n) gld_lds16(ag + (size_t)n*32768, al + n*2048);
#pragma unroll
    for (int n = 0; n < 4; ++n) gld_lds16(bg + (size_t)n*32768, bl + n*2048);
    __syncthreads();                       // implicit vmcnt(0) drain + publish

    int cur = 0;
    for (int k0 = 0; k0 < 1024; k0 += 64) {
        // ---- issue next K-step's stage FIRST (into the other buffer):
        // latency hides under this step's ds_read+MFMA.
        if (k0 + 64 < 1024) {
            const int nb = cur ^ 1;
#pragma unroll
            for (int n = 0; n < 4; ++n)
                gld_lds16(ag + (size_t)n*32768 + k0 + 64, al + nb*8192 + n*2048);
#pragma unroll
            for (int n = 0; n < 4; ++n)
                gld_lds16(bg + (size_t)n*32768 + k0 + 64, bl + nb*8192 + n*2048);
        }
        // ---- compute current buffer
        const ushort_t* Ab = As + cur*8192;
        const ushort_t* Bb = Bs + cur*8192;
#pragma unroll
        for (int sk = 0; sk < 2; ++sk) {
            short8 af[4], bf[4];
#pragma unroll
            for (int i = 0; i < 4; ++i) {
                int row = wm + i*16 + c;
                af[i] = *(const short8*)(Ab + row*64 + (((sk*4 + q) ^ (row & 7)) * 8));
            }
#pragma unroll
            for (int j = 0; j < 4; ++j) {
                int row = wn + j*16 + c;
                bf[j] = *(const short8*)(Bb + row*64 + (((sk*4 + q) ^ (row & 7)) * 8));
            }
#pragma unroll
            for (int i = 0; i < 4; ++i)
#pragma unroll
                for (int j = 0; j < 4; ++j)
                    acc[i][j] = __builtin_amdgcn_mfma_f32_16x16x32_bf16(af[i], bf[j], acc[i][j], 0, 0, 0);
        }
        // one barrier/step: drains vmcnt (next tile landed) and guarantees all
        // waves finished reading buf[cur] before it is overwritten next step.
        __syncthreads();
        cur ^= 1;
    }
}

// ---------------- GEMM core B (pipelined; used by the 1-round gemm_out):
// BM=256 BN=128 BK=64, 8 waves, 3-deep LDS ring, counted vmcnt(6).
__device__ __forceinline__ void gemm_pipe256(const ushort_t* __restrict__ A,
                                             const ushort_t* __restrict__ W,
                                             ushort_t* __restrict__ As,   // 3*16384
                                             ushort_t* __restrict__ Bs,   // 3*8192
                                             int m0, int n0, f32x4 (&acc)[4][4]) {
    const int tid  = threadIdx.x;
    const int wave = tid >> 6, lane = tid & 63;
    const int wm = (wave >> 1) * 64, wn = (wave & 1) * 64;
    const int q = lane >> 4, c = lane & 15;
    const int srow = lane >> 3;            // 0..7
    const int gch  = (lane & 7) ^ srow;    // swizzled source chunk

    const ushort_t* ag = A + (size_t)(m0 + wave * 8 + srow) * 1024 + gch * 8;
    const ushort_t* bg = W + (size_t)(n0 + wave * 8 + srow) * 1024 + gch * 8;
    ushort_t* adst = As + wave * 512;
    ushort_t* bdst = Bs + wave * 512;

    // prologue: stage tile0 -> buf0, tile1 -> buf1 (6 loads each, per thread)
#pragma unroll
    for (int n = 0; n < 4; ++n) gld_lds16(ag + (size_t)n * 65536,      adst + n * 4096);
#pragma unroll
    for (int n = 0; n < 2; ++n) gld_lds16(bg + (size_t)n * 65536,      bdst + n * 4096);
#pragma unroll
    for (int n = 0; n < 4; ++n) gld_lds16(ag + (size_t)n * 65536 + 64, adst + 16384 + n * 4096);
#pragma unroll
    for (int n = 0; n < 2; ++n) gld_lds16(bg + (size_t)n * 65536 + 64, bdst + 8192 + n * 4096);
    asm volatile("s_waitcnt vmcnt(6)" ::: "memory");   // tile0 landed; tile1 in flight
    __builtin_amdgcn_s_barrier();

    const int ch0 = (q ^ (c & 7)) * 8;
    const int ch1 = ((4 + q) ^ (c & 7)) * 8;
    int cur = 0;
    for (int t = 0; t < 16; ++t) {
        const int nx2 = (cur >= 1) ? cur - 1 : 2;          // (t+2)%3
        const ushort_t* ab = As + cur * 16384 + (wm + c) * 64;
        const ushort_t* bb = Bs + cur * 8192  + (wn + c) * 64;
        const int kc = (t + 2) * 64;
        const bool pf = (t < 14);
        short8 af[4], bf[4];

        // ---- phase 0: sk=0 frags, stage A0,A1,B0 of tile t+2
#pragma unroll
        for (int i = 0; i < 4; ++i) af[i] = *(const short8*)(ab + i * 1024 + ch0);
#pragma unroll
        for (int j = 0; j < 4; ++j) bf[j] = *(const short8*)(bb + j * 1024 + ch0);
        if (pf) {
            gld_lds16(ag + kc,           adst + nx2 * 16384);
            gld_lds16(ag + 65536 + kc,   adst + nx2 * 16384 + 4096);
            gld_lds16(bg + kc,           bdst + nx2 * 8192);
        }
        __builtin_amdgcn_s_barrier();
        asm volatile("s_waitcnt lgkmcnt(0)" ::: "memory");
        __builtin_amdgcn_s_setprio(1);
#pragma unroll
        for (int i = 0; i < 4; ++i)
#pragma unroll
            for (int j = 0; j < 4; ++j)
                acc[i][j] = __builtin_amdgcn_mfma_f32_16x16x32_bf16(af[i], bf[j], acc[i][j], 0, 0, 0);
        __builtin_amdgcn_s_setprio(0);
        __builtin_amdgcn_s_barrier();

        // ---- phase 1: sk=1 frags, stage A2,A3,B1 of tile t+2
#pragma unroll
        for (int i = 0; i < 4; ++i) af[i] = *(const short8*)(ab + i * 1024 + ch1);
#pragma unroll
        for (int j = 0; j < 4; ++j) bf[j] = *(const short8*)(bb + j * 1024 + ch1);
        if (pf) {
            gld_lds16(ag + 131072 + kc,  adst + nx2 * 16384 + 8192);
            gld_lds16(ag + 196608 + kc,  adst + nx2 * 16384 + 12288);
            gld_lds16(bg + 65536 + kc,   bdst + nx2 * 8192 + 4096);
        }
        __builtin_amdgcn_s_barrier();
        asm volatile("s_waitcnt lgkmcnt(0)" ::: "memory");
        __builtin_amdgcn_s_setprio(1);
#pragma unroll
        for (int i = 0; i < 4; ++i)
#pragma unroll
            for (int j = 0; j < 4; ++j)
                acc[i][j] = __builtin_amdgcn_mfma_f32_16x16x32_bf16(af[i], bf[j], acc[i][j], 0, 0, 0);
        __builtin_amdgcn_s_setprio(0);
        // counted wait: retire tile t+1's 6 loads, leave tile t+2's 6 in flight
        if (pf) { asm volatile("s_waitcnt vmcnt(6)" ::: "memory"); }
        else    { asm volatile("s_waitcnt vmcnt(0)" ::: "memory"); }
        __builtin_amdgcn_s_barrier();
        cur = (cur == 2) ? 0 : cur + 1;
    }
}

// Fused QKV projection as one logical N=3072 GEMM, 1536 blocks (flattened),
// T1 bijective XCD swizzle. RoPE fused via table; K/V written in flash's
// MFMA-fragment-tiled layouts. Core: A-db (2-phase double-buffered).
__global__ __launch_bounds__(256) void gemm_qkv_kernel(
    const ushort_t* __restrict__ X, const ushort_t* __restrict__ Wq,
    const ushort_t* __restrict__ Wk, const ushort_t* __restrict__ Wv,
    const float2* __restrict__ tab,
    ushort_t* __restrict__ Q, ushort_t* __restrict__ Kt, ushort_t* __restrict__ Vt) {
    __shared__ ushort_t As[2 * 8192];
    __shared__ ushort_t Bs[2 * 8192];
    const int orig = blockIdx.x;                 // 0..1535, 1536 % 8 == 0
    const int wg = (orig & 7) * 192 + (orig >> 3);
    const int my = wg / 24;
    const int n24 = wg - my * 24;
    const int which = n24 >> 3;
    const ushort_t* W = (which == 0) ? Wq : (which == 1) ? Wk : Wv;
    const int m0 = my * 128;
    const int nloc0 = (n24 & 7) * 128;           // 0..896 within the selected matrix

    f32x4 acc[4][4];
#pragma unroll
    for (int i = 0; i < 4; ++i)
#pragma unroll
        for (int j = 0; j < 4; ++j) acc[i][j] = zero4();

    gemm_core_db(X, W, As, Bs, m0, nloc0, acc);

    const int lane = threadIdx.x & 63, wave = threadIdx.x >> 6;
    const int q = lane >> 4, c = lane & 15;
    const int wm = (wave >> 1) * 64, wn = (wave & 1) * 64;
    const float scale = (which == 0) ? 0.18033688011112042f : 1.0f;  // 0.125*log2(e) for Q

#pragma unroll
    for (int i = 0; i < 4; ++i)
#pragma unroll
        for (int j = 0; j < 4; ++j) {
            int nn = nloc0 + wn + j*16 + c;      // col within matrix: h*64+d
            int d = nn & 63, h = nn >> 6;
            int pidx = d >> 1;
            float sgn = (d & 1) ? 1.f : -1.f;
#pragma unroll
            for (int r = 0; r < 4; ++r) {
                int mm = m0 + wm + i*16 + q*4 + r;   // row: b*2048+t
                int b = mm >> 11, t = mm & 2047;
                float val = acc[i][j][r];
                if (which == 0) {      // Q: rope + (B,H,T,64) bf16 row-major
                    float partner = __shfl_xor(val, 1);
                    float2 cs = tab[t * 32 + pidx];
                    val = (val * cs.x + sgn * partner * cs.y) * scale;
                    Q[((size_t)((b << 4) + h) * 2048 + t) * 64 + d] = f2bf(val);
                } else if (which == 1) {  // K: rope + scatter into tiled bf16 layout
                    float partner = __shfl_xor(val, 1);
                    float2 cs = tab[t * 32 + pidx];
                    val = val * cs.x + sgn * partner * cs.y;
                    int kb = t >> 6, jn = (t >> 4) & 3, cc2 = t & 15;
                    int ks2 = d >> 5, qq2 = (d >> 3) & 3, e = d & 7;
                    int lane2 = qq2 * 16 + cc2;
                    Kt[((((size_t)((b << 4) + h) * 32 + kb) * 8 + jn * 2 + ks2) << 9) + lane2 * 8 + e] = f2bf(val);
                } else {               // V: scatter into tiled f16 layout
                    int kb = t >> 6, kl = t & 63;
                    int jn = kl >> 4, qq2 = (kl >> 2) & 3;
                    int e = ((jn & 1) << 2) | (kl & 3);
                    int p = ((d >> 4) << 1) | (jn >> 1);
                    int lane2 = qq2 * 16 + (d & 15);
                    Vt[((((size_t)((b << 4) + h) * 32 + kb) * 8 + p) << 9) + lane2 * 8 + e] = f2h(val);
                }
            }
        }
}

__global__ __launch_bounds__(512) void gemm_out_kernel(
    const ushort_t* __restrict__ A, const ushort_t* __restrict__ Wo,
    float* __restrict__ OUT) {
    __shared__ ushort_t As[3 * 16384];
    __shared__ ushort_t Bs[3 * 8192];
    // 256 blocks (32 m-tiles x 8 n-tiles) = exactly 1/CU, XCD-swizzled
    const int orig = blockIdx.x;
    const int wg = (orig & 7) * 32 + (orig >> 3);
    const int m0 = (wg >> 3) * 256, n0 = (wg & 7) * 128;

    f32x4 acc[4][4];
#pragma unroll
    for (int i = 0; i < 4; ++i)
#pragma unroll
        for (int j = 0; j < 4; ++j) acc[i][j] = zero4();

    gemm_pipe256(A, Wo, As, Bs, m0, n0, acc);

    const int lane = threadIdx.x & 63, wave = threadIdx.x >> 6;
    const int q = lane >> 4, c = lane & 15;
    const int wm = (wave >> 1) * 64, wn = (wave & 1) * 64;
#pragma unroll
    for (int i = 0; i < 4; ++i)
#pragma unroll
        for (int j = 0; j < 4; ++j)
#pragma unroll
            for (int r = 0; r < 4; ++r) {
                int mm = m0 + wm + i*16 + q*4 + r;
                int nn = n0 + wn + j*16 + c;
                OUT[(size_t)mm * 1024 + nn] = acc[i][j][r];
            }
}

// ---------------- Flash attention v8: prefetch double-buffer + PV fused x32 f16.
__global__ __launch_bounds__(256, 3) void flash_kernel(
    const ushort_t* __restrict__ Q, const ushort_t* __restrict__ Kt,
    const ushort_t* __restrict__ Vt, ushort_t* __restrict__ AO) {
    __shared__ ushort_t Ks[2][4096];   // 64x64 bf16 K tiles, fragment-tiled
    __shared__ ushort_t Vs[2][4096];   // 64x64 f16 V tiles, fragment-tiled
    const int bh = blockIdx.x;
    const int c0 = 15 - blockIdx.y;             // LPT: big chunks first
    const int w  = threadIdx.x >> 6, lane = threadIdx.x & 63;
    const int q = lane >> 4, c = lane & 15;
    const int qlo = c0 * 128;
    const int nt  = 2 * c0 + 2;                 // 64-key tiles
    const int wq0 = qlo + w * 32;               // this wave's first query
    const int b = bh >> 4, hh = bh & 15;

    const ushort_t* Qp = Q + (size_t)bh * 131072;
    const ushort_t* kt0 = Kt + (size_t)bh * 131072;
    const ushort_t* vt0 = Vt + (size_t)bh * 131072;

    short8 qf[2][2];
#pragma unroll
    for (int m = 0; m < 2; ++m)
#pragma unroll
        for (int ks = 0; ks < 2; ++ks)
            qf[m][ks] = *(const short8*)(Qp + (size_t)(wq0 + m*16 + c) * 64 + ks * 32 + q * 8);

    f32x4 ot[2][4];
#pragma unroll
    for (int m = 0; m < 2; ++m)
#pragma unroll
        for (int dj = 0; dj < 4; ++dj) ot[m][dj] = zero4();
    float lpart[2] = {0.f, 0.f};

    // prologue: stage tile 0 -> buf 0
#pragma unroll
    for (int s = 0; s < 2; ++s) {
        gld_lds16(kt0 + (s*4 + w)*512 + lane*8, &Ks[0][(s*4 + w)*512]);
        gld_lds16(vt0 + (s*4 + w)*512 + lane*8, &Vs[0][(s*4 + w)*512]);
    }
    asm volatile("s_waitcnt vmcnt(0)" ::: "memory");
    __syncthreads();

    for (int kb = 0; kb < nt; ++kb) {
        const int cur = kb & 1;
        // ---- issue next tile's stage FIRST: latency hides under this tile's compute
        if (kb + 1 < nt) {
            const ushort_t* kt = kt0 + (size_t)(kb + 1) * 4096;
            const ushort_t* vt = vt0 + (size_t)(kb + 1) * 4096;
#pragma unroll
            for (int s = 0; s < 2; ++s) {
                gld_lds16(kt + (s*4 + w)*512 + lane*8, &Ks[cur ^ 1][(s*4 + w)*512]);
                gld_lds16(vt + (s*4 + w)*512 + lane*8, &Vs[cur ^ 1][(s*4 + w)*512]);
            }
        }

        if (kb * 64 <= wq0 + 31) {              // not fully masked for this wave
            const ushort_t* Kb = &Ks[cur][0];
            const ushort_t* Vb = &Vs[cur][0];
            // ---- S^T = K Q^T : row=key(q*4+r), col=query(c)
            f32x4 st[2][4];
#pragma unroll
            for (int jn = 0; jn < 4; ++jn) {
                short8 kf0 = *(const short8*)(Kb + (jn*2+0)*512 + lane*8);
                short8 kf1 = *(const short8*)(Kb + (jn*2+1)*512 + lane*8);
#pragma unroll
                for (int m = 0; m < 2; ++m) {
                    f32x4 t0 = __builtin_amdgcn_mfma_f32_16x16x32_bf16(kf0, qf[m][0], zero4(), 0, 0, 0);
                    st[m][jn] = __builtin_amdgcn_mfma_f32_16x16x32_bf16(kf1, qf[m][1], t0, 0, 0, 0);
                }
            }
            if (kb * 64 + 63 > wq0) {           // partial (diagonal) tile: mask
#pragma unroll
                for (int m = 0; m < 2; ++m) {
                    int query = wq0 + m * 16 + c;
#pragma unroll
                    for (int jn = 0; jn < 4; ++jn)
#pragma unroll
                        for (int r = 0; r < 4; ++r)
                            if (kb * 64 + jn * 16 + q * 4 + r > query) st[m][jn][r] = -1e30f;
                }
            }
            // ---- p = exp2(s'); per-lane l partials; pack f16 B-frags
            half4 pa[2][4];
#pragma unroll
            for (int m = 0; m < 2; ++m)
#pragma unroll
                for (int jn = 0; jn < 4; ++jn) {
                    float p0 = exp2f(st[m][jn][0]), p1 = exp2f(st[m][jn][1]);
                    float p2 = exp2f(st[m][jn][2]), p3 = exp2f(st[m][jn][3]);
                    lpart[m] += (p0 + p1) + (p2 + p3);
                    pa[m][jn] = pk4(p0, p1, p2, p3);
                }
            // ---- O^T += V^T P^T  (fused x32: one MFMA per (jnp,dj,m))
#pragma unroll
            for (int jnp = 0; jnp < 2; ++jnp)
#pragma unroll
                for (int dj = 0; dj < 4; ++dj) {
                    half8 vv8 = __builtin_bit_cast(half8,
                        *(const short8*)(Vb + (dj*2 + jnp)*512 + lane*8));
#pragma unroll
                    for (int m = 0; m < 2; ++m) {
                        half4x2 pb;
                        pb.lo = pa[m][2*jnp];
                        pb.hi = pa[m][2*jnp+1];
                        ot[m][dj] = __builtin_amdgcn_mfma_f32_16x16x32_f16(
                            vv8, __builtin_bit_cast(half8, pb), ot[m][dj], 0, 0, 0);
                    }
                }
        }

        // next tile landed + all waves done reading buf[cur^1] (writes target it next iter)
        asm volatile("s_waitcnt vmcnt(0)" ::: "memory");
        __syncthreads();
    }

    // ---- epilogue: quad-reduce l (keys on lanes c,c+16,c+32,c+48), normalize, store
#pragma unroll
    for (int m = 0; m < 2; ++m) {
        float l = lpart[m];
        l += __shfl_xor(l, 16);
        l += __shfl_xor(l, 32);
        float inv = 1.f / l;
        int t = wq0 + m * 16 + c;
        ushort_t* base = AO + ((size_t)b * 2048 + t) * 1024 + hh * 64;
#pragma unroll
        for (int dj = 0; dj < 4; ++dj) {
            ushort4 o;
            o.x = f2bf(ot[m][dj][0] * inv);
            o.y = f2bf(ot[m][dj][1] * inv);
            o.z = f2bf(ot[m][dj][2] * inv);
            o.w = f2bf(ot[m][dj][3] * inv);
            *(ushort4*)(base + dj * 16 + q * 4) = o;
        }
    }
}

extern "C" void kernel_launch(void* const* d_in, const int* in_sizes, int n_in,
                              void* d_out, int out_size, void* d_ws, size_t ws_size,
                              hipStream_t stream) {
    const float* x  = (const float*)d_in[0];
    const float* Wq = (const float*)d_in[2];
    const float* Wk = (const float*)d_in[3];
    const float* Wv = (const float*)d_in[4];
    const float* Wo = (const float*)d_in[5];
    float* out = (float*)d_out;

    ushort_t* ws  = (ushort_t*)d_ws;
    ushort_t* Xb  = ws;                 // 8192x1024 bf16; reused as AO after projections
    ushort_t* Qb  = ws + 8388608;
    ushort_t* Ktb = ws + 16777216;      // bf16, MFMA-fragment-tiled (bh,kb,p,lane,8)
    ushort_t* Vtb = ws + 25165824;      // f16,  MFMA-fragment-tiled (bh,kb,p,lane,8)
    ushort_t* Wqb = ws + 33554432;
    ushort_t* Wkb = Wqb + 1048576;
    ushort_t* Wvb = Wkb + 1048576;
    ushort_t* Wob = Wvb + 1048576;
    float2*   tab = (float2*)(ws + 37748736);   // 512 KB rope table

    cvt_all<<<12544, 256, 0, stream>>>(x, Wq, Wk, Wv, Wo, Xb, Wqb, Wkb, Wvb, Wob, tab);

    // fused QKV: one logical N=3072 GEMM; 128x128 2-phase double-buffered core
    gemm_qkv_kernel<<<1536, 256, 0, stream>>>(Xb, Wqb, Wkb, Wvb, tab, Qb, Ktb, Vtb);

    flash_kernel<<<dim3(64, 16), 256, 0, stream>>>(Qb, Ktb, Vtb, Xb);

    gemm_out_kernel<<<256, 512, 0, stream>>>(Xb, Wob, out);
}

// Round 7
// 271.938 us; speedup vs baseline: 1.1977x; 1.0240x over previous
//
#include <hip/hip_runtime.h>
#include <cstdint>
#include <cstddef>

typedef unsigned short ushort_t;
typedef __attribute__((ext_vector_type(8))) short short8;
typedef __attribute__((ext_vector_type(4))) float f32x4;
typedef __attribute__((ext_vector_type(4))) _Float16 half4;
typedef __attribute__((ext_vector_type(8))) _Float16 half8;
typedef __attribute__((ext_vector_type(2))) _Float16 half2;
typedef __attribute__((ext_vector_type(2))) __fp16 fp16v2;
struct half4x2 { half4 lo, hi; };
struct half2x2 { half2 lo, hi; };

__device__ __forceinline__ unsigned short f2bf(float f) {
    unsigned u = __float_as_uint(f);
    u += 0x7fffu + ((u >> 16) & 1u);
    return (unsigned short)(u >> 16);
}
__device__ __forceinline__ float bf2f(unsigned short h) {
    return __uint_as_float((unsigned)h << 16);
}
__device__ __forceinline__ ushort_t f2h(float f) {
    _Float16 h = (_Float16)f;
    return __builtin_bit_cast(unsigned short, h);
}
__device__ __forceinline__ f32x4 zero4() {
    f32x4 z; z[0]=0.f; z[1]=0.f; z[2]=0.f; z[3]=0.f; return z;
}
__device__ __forceinline__ half4 pk4(float a, float b, float cc, float d) {
    half2x2 t;
    t.lo = __builtin_bit_cast(half2, (fp16v2)__builtin_amdgcn_cvt_pkrtz(a, b));
    t.hi = __builtin_bit_cast(half2, (fp16v2)__builtin_amdgcn_cvt_pkrtz(cc, d));
    return __builtin_bit_cast(half4, t);
}
__device__ __forceinline__ void gld_lds16(const ushort_t* g, ushort_t* l) {
    __builtin_amdgcn_global_load_lds(
        (const __attribute__((address_space(1))) void*)g,
        (__attribute__((address_space(3))) void*)l, 16, 0, 0);
}

// ---------------- fused fp32->bf16 convert (x + 4 weights) + rope table, one launch ----------------
__global__ void cvt_all(const float* __restrict__ x,
                        const float* __restrict__ wq, const float* __restrict__ wk,
                        const float* __restrict__ wv, const float* __restrict__ wo,
                        ushort_t* __restrict__ xb,
                        ushort_t* __restrict__ wqb, ushort_t* __restrict__ wkb,
                        ushort_t* __restrict__ wvb, ushort_t* __restrict__ wob,
                        float2* __restrict__ tab) {
    int idx = blockIdx.x * 256 + threadIdx.x;   // grid 12544 blocks exactly
    if (idx >= 3145728) {                        // rope table: 65536 entries
        int i = idx - 3145728;
        int t = i >> 5, p = i & 31;
        float freq = __expf((float)p * -0.2878231366242557f);  // 10000^(-p/32)
        float sn, cs;
        sincosf((float)t * freq, &sn, &cs);
        tab[i] = make_float2(cs, sn);
        return;
    }
    const float* src; ushort_t* dst; int off;
    if (idx < 2097152) { src = x; dst = xb; off = idx; }
    else {
        int r = idx - 2097152;
        int w = r >> 18;
        off = r & 262143;
        src = (w == 0) ? wq : (w == 1) ? wk : (w == 2) ? wv : wo;
        dst = (w == 0) ? wqb : (w == 1) ? wkb : (w == 2) ? wvb : wob;
    }
    float4 v = ((const float4*)src)[off];
    ushort_t o[4];
    o[0] = f2bf(v.x); o[1] = f2bf(v.y); o[2] = f2bf(v.z); o[3] = f2bf(v.w);
    *(ushort4*)(dst + 4*(size_t)off) = *(const ushort4*)o;
}

// ---------------- GEMM core A-db32: BM=BN=128, BK=32, 4 waves, 2-phase
// double-buffer (32 KiB LDS -> 4-5 blocks/CU co-residency, the m114 lever).
// Same template as R6's winning core, halved K-step. XOR swizzle for the 64B
// row stride: chunk' = q ^ ((row>>1)&3) -> 2 lanes/bank (free, m136).
// C = A(Mx1024) W(Nx1024)^T.
__device__ __forceinline__ void gemm_core_db32(const ushort_t* __restrict__ A,
                                               const ushort_t* __restrict__ W,
                                               ushort_t* As, ushort_t* Bs,  // each 2*4096 ushorts
                                               int m0, int n0, f32x4 (&acc)[4][4]) {
    const int tid  = threadIdx.x;
    const int wave = tid >> 6, lane = tid & 63;
    const int wm = (wave >> 1) * 64, wn = (wave & 1) * 64;
    const int q = lane >> 4, c = lane & 15;
    const int srow = lane >> 2;                      // 0..15: row within 16-row group
    const int gch  = (lane & 3) ^ ((lane >> 3) & 3); // source chunk = (lane&3)^((srow>>1)&3)

    // staging: wave w covers rows {p*64 + w*16 + srow} for p=0,1 (A and B)
    const ushort_t* ag0 = A + (size_t)(m0 +      wave*16 + srow) * 1024 + gch*8;
    const ushort_t* ag1 = A + (size_t)(m0 + 64 + wave*16 + srow) * 1024 + gch*8;
    const ushort_t* bg0 = W + (size_t)(n0 +      wave*16 + srow) * 1024 + gch*8;
    const ushort_t* bg1 = W + (size_t)(n0 + 64 + wave*16 + srow) * 1024 + gch*8;
    // LDS dest is wave-uniform base; HW adds lane*16B = rows wave*16+(lane>>2), chunk lane&3
    ushort_t* a0 = As + wave*512;
    ushort_t* a1 = As + 2048 + wave*512;
    ushort_t* b0 = Bs + wave*512;
    ushort_t* b1 = Bs + 2048 + wave*512;

    // prologue: stage K-step 0 into buffer 0
    gld_lds16(ag0, a0); gld_lds16(ag1, a1);
    gld_lds16(bg0, b0); gld_lds16(bg1, b1);
    __syncthreads();                       // drain + publish

    const int ch = (q ^ ((c >> 1) & 3)) * 8;   // read-side swizzled chunk (uniform/lane)
    int cur = 0;
    for (int t = 0; t < 32; ++t) {
        // ---- issue next K-step's stage FIRST (other buffer)
        if (t + 1 < 32) {
            const int nb = cur ^ 1;
            const int kc = (t + 1) * 32;
            gld_lds16(ag0 + kc, a0 + nb*4096);
            gld_lds16(ag1 + kc, a1 + nb*4096);
            gld_lds16(bg0 + kc, b0 + nb*4096);
            gld_lds16(bg1 + kc, b1 + nb*4096);
        }
        // ---- compute current buffer: 16 MFMAs, 8 ds_read_b128
        const ushort_t* Ab = As + cur*4096;
        const ushort_t* Bb = Bs + cur*4096;
        short8 af[4], bf[4];
#pragma unroll
        for (int i = 0; i < 4; ++i)
            af[i] = *(const short8*)(Ab + (wm + i*16 + c)*32 + ch);
#pragma unroll
        for (int j = 0; j < 4; ++j)
            bf[j] = *(const short8*)(Bb + (wn + j*16 + c)*32 + ch);
#pragma unroll
        for (int i = 0; i < 4; ++i)
#pragma unroll
            for (int j = 0; j < 4; ++j)
                acc[i][j] = __builtin_amdgcn_mfma_f32_16x16x32_bf16(af[i], bf[j], acc[i][j], 0, 0, 0);
        // one barrier/step: drains next tile's loads (aged by this compute) and
        // guards buf[cur] against next step's overwrite.
        __syncthreads();
        cur ^= 1;
    }
}

// ---------------- GEMM core B (pipelined; used by the 1-round gemm_out):
// BM=256 BN=128 BK=64, 8 waves, 3-deep LDS ring, counted vmcnt(6).
__device__ __forceinline__ void gemm_pipe256(const ushort_t* __restrict__ A,
                                             const ushort_t* __restrict__ W,
                                             ushort_t* __restrict__ As,   // 3*16384
                                             ushort_t* __restrict__ Bs,   // 3*8192
                                             int m0, int n0, f32x4 (&acc)[4][4]) {
    const int tid  = threadIdx.x;
    const int wave = tid >> 6, lane = tid & 63;
    const int wm = (wave >> 1) * 64, wn = (wave & 1) * 64;
    const int q = lane >> 4, c = lane & 15;
    const int srow = lane >> 3;            // 0..7
    const int gch  = (lane & 7) ^ srow;    // swizzled source chunk

    const ushort_t* ag = A + (size_t)(m0 + wave * 8 + srow) * 1024 + gch * 8;
    const ushort_t* bg = W + (size_t)(n0 + wave * 8 + srow) * 1024 + gch * 8;
    ushort_t* adst = As + wave * 512;
    ushort_t* bdst = Bs + wave * 512;

    // prologue: stage tile0 -> buf0, tile1 -> buf1 (6 loads each, per thread)
#pragma unroll
    for (int n = 0; n < 4; ++n) gld_lds16(ag + (size_t)n * 65536,      adst + n * 4096);
#pragma unroll
    for (int n = 0; n < 2; ++n) gld_lds16(bg + (size_t)n * 65536,      bdst + n * 4096);
#pragma unroll
    for (int n = 0; n < 4; ++n) gld_lds16(ag + (size_t)n * 65536 + 64, adst + 16384 + n * 4096);
#pragma unroll
    for (int n = 0; n < 2; ++n) gld_lds16(bg + (size_t)n * 65536 + 64, bdst + 8192 + n * 4096);
    asm volatile("s_waitcnt vmcnt(6)" ::: "memory");   // tile0 landed; tile1 in flight
    __builtin_amdgcn_s_barrier();

    const int ch0 = (q ^ (c & 7)) * 8;
    const int ch1 = ((4 + q) ^ (c & 7)) * 8;
    int cur = 0;
    for (int t = 0; t < 16; ++t) {
        const int nx2 = (cur >= 1) ? cur - 1 : 2;          // (t+2)%3
        const ushort_t* ab = As + cur * 16384 + (wm + c) * 64;
        const ushort_t* bb = Bs + cur * 8192  + (wn + c) * 64;
        const int kc = (t + 2) * 64;
        const bool pf = (t < 14);
        short8 af[4], bf[4];

        // ---- phase 0: sk=0 frags, stage A0,A1,B0 of tile t+2
#pragma unroll
        for (int i = 0; i < 4; ++i) af[i] = *(const short8*)(ab + i * 1024 + ch0);
#pragma unroll
        for (int j = 0; j < 4; ++j) bf[j] = *(const short8*)(bb + j * 1024 + ch0);
        if (pf) {
            gld_lds16(ag + kc,           adst + nx2 * 16384);
            gld_lds16(ag + 65536 + kc,   adst + nx2 * 16384 + 4096);
            gld_lds16(bg + kc,           bdst + nx2 * 8192);
        }
        __builtin_amdgcn_s_barrier();
        asm volatile("s_waitcnt lgkmcnt(0)" ::: "memory");
        __builtin_amdgcn_s_setprio(1);
#pragma unroll
        for (int i = 0; i < 4; ++i)
#pragma unroll
            for (int j = 0; j < 4; ++j)
                acc[i][j] = __builtin_amdgcn_mfma_f32_16x16x32_bf16(af[i], bf[j], acc[i][j], 0, 0, 0);
        __builtin_amdgcn_s_setprio(0);
        __builtin_amdgcn_s_barrier();

        // ---- phase 1: sk=1 frags, stage A2,A3,B1 of tile t+2
#pragma unroll
        for (int i = 0; i < 4; ++i) af[i] = *(const short8*)(ab + i * 1024 + ch1);
#pragma unroll
        for (int j = 0; j < 4; ++j) bf[j] = *(const short8*)(bb + j * 1024 + ch1);
        if (pf) {
            gld_lds16(ag + 131072 + kc,  adst + nx2 * 16384 + 8192);
            gld_lds16(ag + 196608 + kc,  adst + nx2 * 16384 + 12288);
            gld_lds16(bg + 65536 + kc,   bdst + nx2 * 8192 + 4096);
        }
        __builtin_amdgcn_s_barrier();
        asm volatile("s_waitcnt lgkmcnt(0)" ::: "memory");
        __builtin_amdgcn_s_setprio(1);
#pragma unroll
        for (int i = 0; i < 4; ++i)
#pragma unroll
            for (int j = 0; j < 4; ++j)
                acc[i][j] = __builtin_amdgcn_mfma_f32_16x16x32_bf16(af[i], bf[j], acc[i][j], 0, 0, 0);
        __builtin_amdgcn_s_setprio(0);
        // counted wait: retire tile t+1's 6 loads, leave tile t+2's 6 in flight
        if (pf) { asm volatile("s_waitcnt vmcnt(6)" ::: "memory"); }
        else    { asm volatile("s_waitcnt vmcnt(0)" ::: "memory"); }
        __builtin_amdgcn_s_barrier();
        cur = (cur == 2) ? 0 : cur + 1;
    }
}

// Fused QKV projection as one logical N=3072 GEMM, 1536 blocks (flattened),
// T1 bijective XCD swizzle. RoPE fused via table; K/V written in flash's
// MFMA-fragment-tiled layouts. Core: A-db32 (2-phase dbuf, BK=32, 4-5 blk/CU).
__global__ __launch_bounds__(256) void gemm_qkv_kernel(
    const ushort_t* __restrict__ X, const ushort_t* __restrict__ Wq,
    const ushort_t* __restrict__ Wk, const ushort_t* __restrict__ Wv,
    const float2* __restrict__ tab,
    ushort_t* __restrict__ Q, ushort_t* __restrict__ Kt, ushort_t* __restrict__ Vt) {
    __shared__ ushort_t As[2 * 4096];
    __shared__ ushort_t Bs[2 * 4096];
    const int orig = blockIdx.x;                 // 0..1535, 1536 % 8 == 0
    const int wg = (orig & 7) * 192 + (orig >> 3);
    const int my = wg / 24;
    const int n24 = wg - my * 24;
    const int which = n24 >> 3;
    const ushort_t* W = (which == 0) ? Wq : (which == 1) ? Wk : Wv;
    const int m0 = my * 128;
    const int nloc0 = (n24 & 7) * 128;           // 0..896 within the selected matrix

    f32x4 acc[4][4];
#pragma unroll
    for (int i = 0; i < 4; ++i)
#pragma unroll
        for (int j = 0; j < 4; ++j) acc[i][j] = zero4();

    gemm_core_db32(X, W, As, Bs, m0, nloc0, acc);

    const int lane = threadIdx.x & 63, wave = threadIdx.x >> 6;
    const int q = lane >> 4, c = lane & 15;
    const int wm = (wave >> 1) * 64, wn = (wave & 1) * 64;
    const float scale = (which == 0) ? 0.18033688011112042f : 1.0f;  // 0.125*log2(e) for Q

#pragma unroll
    for (int i = 0; i < 4; ++i)
#pragma unroll
        for (int j = 0; j < 4; ++j) {
            int nn = nloc0 + wn + j*16 + c;      // col within matrix: h*64+d
            int d = nn & 63, h = nn >> 6;
            int pidx = d >> 1;
            float sgn = (d & 1) ? 1.f : -1.f;
#pragma unroll
            for (int r = 0; r < 4; ++r) {
                int mm = m0 + wm + i*16 + q*4 + r;   // row: b*2048+t
                int b = mm >> 11, t = mm & 2047;
                float val = acc[i][j][r];
                if (which == 0) {      // Q: rope + (B,H,T,64) bf16 row-major
                    float partner = __shfl_xor(val, 1);
                    float2 cs = tab[t * 32 + pidx];
                    val = (val * cs.x + sgn * partner * cs.y) * scale;
                    Q[((size_t)((b << 4) + h) * 2048 + t) * 64 + d] = f2bf(val);
                } else if (which == 1) {  // K: rope + scatter into tiled bf16 layout
                    float partner = __shfl_xor(val, 1);
                    float2 cs = tab[t * 32 + pidx];
                    val = val * cs.x + sgn * partner * cs.y;
                    int kb = t >> 6, jn = (t >> 4) & 3, cc2 = t & 15;
                    int ks2 = d >> 5, qq2 = (d >> 3) & 3, e = d & 7;
                    int lane2 = qq2 * 16 + cc2;
                    Kt[((((size_t)((b << 4) + h) * 32 + kb) * 8 + jn * 2 + ks2) << 9) + lane2 * 8 + e] = f2bf(val);
                } else {               // V: scatter into tiled f16 layout
                    int kb = t >> 6, kl = t & 63;
                    int jn = kl >> 4, qq2 = (kl >> 2) & 3;
                    int e = ((jn & 1) << 2) | (kl & 3);
                    int p = ((d >> 4) << 1) | (jn >> 1);
                    int lane2 = qq2 * 16 + (d & 15);
                    Vt[((((size_t)((b << 4) + h) * 32 + kb) * 8 + p) << 9) + lane2 * 8 + e] = f2h(val);
                }
            }
        }
}

__global__ __launch_bounds__(512) void gemm_out_kernel(
    const ushort_t* __restrict__ A, const ushort_t* __restrict__ Wo,
    float* __restrict__ OUT) {
    __shared__ ushort_t As[3 * 16384];
    __shared__ ushort_t Bs[3 * 8192];
    // 256 blocks (32 m-tiles x 8 n-tiles) = exactly 1/CU, XCD-swizzled
    const int orig = blockIdx.x;
    const int wg = (orig & 7) * 32 + (orig >> 3);
    const int m0 = (wg >> 3) * 256, n0 = (wg & 7) * 128;

    f32x4 acc[4][4];
#pragma unroll
    for (int i = 0; i < 4; ++i)
#pragma unroll
        for (int j = 0; j < 4; ++j) acc[i][j] = zero4();

    gemm_pipe256(A, Wo, As, Bs, m0, n0, acc);

    const int lane = threadIdx.x & 63, wave = threadIdx.x >> 6;
    const int q = lane >> 4, c = lane & 15;
    const int wm = (wave >> 1) * 64, wn = (wave & 1) * 64;
#pragma unroll
    for (int i = 0; i < 4; ++i)
#pragma unroll
        for (int j = 0; j < 4; ++j)
#pragma unroll
            for (int r = 0; r < 4; ++r) {
                int mm = m0 + wm + i*16 + q*4 + r;
                int nn = n0 + wn + j*16 + c;
                OUT[(size_t)mm * 1024 + nn] = acc[i][j][r];
            }
}

// ---------------- Flash attention v8: prefetch double-buffer + PV fused x32 f16.
__global__ __launch_bounds__(256, 3) void flash_kernel(
    const ushort_t* __restrict__ Q, const ushort_t* __restrict__ Kt,
    const ushort_t* __restrict__ Vt, ushort_t* __restrict__ AO) {
    __shared__ ushort_t Ks[2][4096];   // 64x64 bf16 K tiles, fragment-tiled
    __shared__ ushort_t Vs[2][4096];   // 64x64 f16 V tiles, fragment-tiled
    const int bh = blockIdx.x;
    const int c0 = 15 - blockIdx.y;             // LPT: big chunks first
    const int w  = threadIdx.x >> 6, lane = threadIdx.x & 63;
    const int q = lane >> 4, c = lane & 15;
    const int qlo = c0 * 128;
    const int nt  = 2 * c0 + 2;                 // 64-key tiles
    const int wq0 = qlo + w * 32;               // this wave's first query
    const int b = bh >> 4, hh = bh & 15;

    const ushort_t* Qp = Q + (size_t)bh * 131072;
    const ushort_t* kt0 = Kt + (size_t)bh * 131072;
    const ushort_t* vt0 = Vt + (size_t)bh * 131072;

    short8 qf[2][2];
#pragma unroll
    for (int m = 0; m < 2; ++m)
#pragma unroll
        for (int ks = 0; ks < 2; ++ks)
            qf[m][ks] = *(const short8*)(Qp + (size_t)(wq0 + m*16 + c) * 64 + ks * 32 + q * 8);

    f32x4 ot[2][4];
#pragma unroll
    for (int m = 0; m < 2; ++m)
#pragma unroll
        for (int dj = 0; dj < 4; ++dj) ot[m][dj] = zero4();
    float lpart[2] = {0.f, 0.f};

    // prologue: stage tile 0 -> buf 0
#pragma unroll
    for (int s = 0; s < 2; ++s) {
        gld_lds16(kt0 + (s*4 + w)*512 + lane*8, &Ks[0][(s*4 + w)*512]);
        gld_lds16(vt0 + (s*4 + w)*512 + lane*8, &Vs[0][(s*4 + w)*512]);
    }
    asm volatile("s_waitcnt vmcnt(0)" ::: "memory");
    __syncthreads();

    for (int kb = 0; kb < nt; ++kb) {
        const int cur = kb & 1;
        // ---- issue next tile's stage FIRST: latency hides under this tile's compute
        if (kb + 1 < nt) {
            const ushort_t* kt = kt0 + (size_t)(kb + 1) * 4096;
            const ushort_t* vt = vt0 + (size_t)(kb + 1) * 4096;
#pragma unroll
            for (int s = 0; s < 2; ++s) {
                gld_lds16(kt + (s*4 + w)*512 + lane*8, &Ks[cur ^ 1][(s*4 + w)*512]);
                gld_lds16(vt + (s*4 + w)*512 + lane*8, &Vs[cur ^ 1][(s*4 + w)*512]);
            }
        }

        if (kb * 64 <= wq0 + 31) {              // not fully masked for this wave
            const ushort_t* Kb = &Ks[cur][0];
            const ushort_t* Vb = &Vs[cur][0];
            // ---- S^T = K Q^T : row=key(q*4+r), col=query(c)
            f32x4 st[2][4];
#pragma unroll
            for (int jn = 0; jn < 4; ++jn) {
                short8 kf0 = *(const short8*)(Kb + (jn*2+0)*512 + lane*8);
                short8 kf1 = *(const short8*)(Kb + (jn*2+1)*512 + lane*8);
#pragma unroll
                for (int m = 0; m < 2; ++m) {
                    f32x4 t0 = __builtin_amdgcn_mfma_f32_16x16x32_bf16(kf0, qf[m][0], zero4(), 0, 0, 0);
                    st[m][jn] = __builtin_amdgcn_mfma_f32_16x16x32_bf16(kf1, qf[m][1], t0, 0, 0, 0);
                }
            }
            if (kb * 64 + 63 > wq0) {           // partial (diagonal) tile: mask
#pragma unroll
                for (int m = 0; m < 2; ++m) {
                    int query = wq0 + m * 16 + c;
#pragma unroll
                    for (int jn = 0; jn < 4; ++jn)
#pragma unroll
                        for (int r = 0; r < 4; ++r)
                            if (kb * 64 + jn * 16 + q * 4 + r > query) st[m][jn][r] = -1e30f;
                }
            }
            // ---- p = exp2(s'); per-lane l partials; pack f16 B-frags
            half4 pa[2][4];
#pragma unroll
            for (int m = 0; m < 2; ++m)
#pragma unroll
                for (int jn = 0; jn < 4; ++jn) {
                    float p0 = exp2f(st[m][jn][0]), p1 = exp2f(st[m][jn][1]);
                    float p2 = exp2f(st[m][jn][2]), p3 = exp2f(st[m][jn][3]);
                    lpart[m] += (p0 + p1) + (p2 + p3);
                    pa[m][jn] = pk4(p0, p1, p2, p3);
                }
            // ---- O^T += V^T P^T  (fused x32: one MFMA per (jnp,dj,m))
#pragma unroll
            for (int jnp = 0; jnp < 2; ++jnp)
#pragma unroll
                for (int dj = 0; dj < 4; ++dj) {
                    half8 vv8 = __builtin_bit_cast(half8,
                        *(const short8*)(Vb + (dj*2 + jnp)*512 + lane*8));
#pragma unroll
                    for (int m = 0; m < 2; ++m) {
                        half4x2 pb;
                        pb.lo = pa[m][2*jnp];
                        pb.hi = pa[m][2*jnp+1];
                        ot[m][dj] = __builtin_amdgcn_mfma_f32_16x16x32_f16(
                            vv8, __builtin_bit_cast(half8, pb), ot[m][dj], 0, 0, 0);
                    }
                }
        }

        // next tile landed + all waves done reading buf[cur^1] (writes target it next iter)
        asm volatile("s_waitcnt vmcnt(0)" ::: "memory");
        __syncthreads();
    }

    // ---- epilogue: quad-reduce l (keys on lanes c,c+16,c+32,c+48), normalize, store
#pragma unroll
    for (int m = 0; m < 2; ++m) {
        float l = lpart[m];
        l += __shfl_xor(l, 16);
        l += __shfl_xor(l, 32);
        float inv = 1.f / l;
        int t = wq0 + m * 16 + c;
        ushort_t* base = AO + ((size_t)b * 2048 + t) * 1024 + hh * 64;
#pragma unroll
        for (int dj = 0; dj < 4; ++dj) {
            ushort4 o;
            o.x = f2bf(ot[m][dj][0] * inv);
            o.y = f2bf(ot[m][dj][1] * inv);
            o.z = f2bf(ot[m][dj][2] * inv);
            o.w = f2bf(ot[m][dj][3] * inv);
            *(ushort4*)(base + dj * 16 + q * 4) = o;
        }
    }
}

extern "C" void kernel_launch(void* const* d_in, const int* in_sizes, int n_in,
                              void* d_out, int out_size, void* d_ws, size_t ws_size,
                              hipStream_t stream) {
    const float* x  = (const float*)d_in[0];
    const float* Wq = (const float*)d_in[2];
    const float* Wk = (const float*)d_in[3];
    const float* Wv = (const float*)d_in[4];
    const float* Wo = (const float*)d_in[5];
    float* out = (float*)d_out;

    ushort_t* ws  = (ushort_t*)d_ws;
    ushort_t* Xb  = ws;                 // 8192x1024 bf16; reused as AO after projections
    ushort_t* Qb  = ws + 8388608;
    ushort_t* Ktb = ws + 16777216;      // bf16, MFMA-fragment-tiled (bh,kb,p,lane,8)
    ushort_t* Vtb = ws + 25165824;      // f16,  MFMA-fragment-tiled (bh,kb,p,lane,8)
    ushort_t* Wqb = ws + 33554432;
    ushort_t* Wkb = Wqb + 1048576;
    ushort_t* Wvb = Wkb + 1048576;
    ushort_t* Wob = Wvb + 1048576;
    float2*   tab = (float2*)(ws + 37748736);   // 512 KB rope table

    cvt_all<<<12544, 256, 0, stream>>>(x, Wq, Wk, Wv, Wo, Xb, Wqb, Wkb, Wvb, Wob, tab);

    // fused QKV: one logical N=3072 GEMM; 128x128 BK=32 dbuf core + XCD swizzle
    gemm_qkv_kernel<<<1536, 256, 0, stream>>>(Xb, Wqb, Wkb, Wvb, tab, Qb, Ktb, Vtb);

    flash_kernel<<<dim3(64, 16), 256, 0, stream>>>(Qb, Ktb, Vtb, Xb);

    gemm_out_kernel<<<256, 512, 0, stream>>>(Xb, Wob, out);
}